// Round 1
// baseline (2911.814 us; speedup 1.0000x reference)
//
#include <hip/hip_runtime.h>
#include <math.h>

#define NN 8192
#define NE 65536
#define SQRT3F 1.7320508075688772f
#define PW 0.17677669529663687f      // 1/sqrt(32) == 0.25/sqrt(2)
#define GSTEP (10.0f/31.0f)
#define GCOEFF (-0.5f/(GSTEP*GSTEP))

// ---------------- transpose c0_w2 (48x512 -> 512x48), c1_w2 (48x1280 -> 1280x48) ----------------
__global__ __launch_bounds__(256) void k_transpose(const float* __restrict__ w0, float* __restrict__ w0t,
                                                   const float* __restrict__ w1, float* __restrict__ w1t) {
    int idx = blockIdx.x * 256 + threadIdx.x;          // grid covers 61440
    if (idx < 48 * 512) {
        int h = idx >> 9, k = idx & 511;
        w0t[k * 48 + h] = w0[idx];
    }
    if (idx < 48 * 1280) {
        int h = idx / 1280, k = idx - h * 1280;
        w1t[k * 48 + h] = w1[idx];
    }
}

// ---------------- node MLP: x(32) -> 16 -> 16 ----------------
__global__ __launch_bounds__(256) void k_node_mlp(const float* __restrict__ xr, const float* __restrict__ xp,
                                                  float* __restrict__ h16,
                                                  const float* __restrict__ w1, const float* __restrict__ b1,
                                                  const float* __restrict__ w2, const float* __restrict__ b2) {
    int mol = blockIdx.y;
    const float* x = mol ? xp : xr;
    float* h = h16 + (size_t)mol * NN * 16;
    int v = blockIdx.x * 256 + threadIdx.x;
    float xi[32];
#pragma unroll
    for (int i = 0; i < 32; i++) xi[i] = x[v * 32 + i];
    float a[16];
#pragma unroll
    for (int j = 0; j < 16; j++) a[j] = b1[j];
#pragma unroll
    for (int i = 0; i < 32; i++) {
#pragma unroll
        for (int j = 0; j < 16; j++) a[j] = fmaf(xi[i], w1[i * 16 + j], a[j]);
    }
#pragma unroll
    for (int j = 0; j < 16; j++) a[j] = fmaxf(a[j], 0.f);
    float o[16];
#pragma unroll
    for (int j = 0; j < 16; j++) o[j] = b2[j];
#pragma unroll
    for (int i = 0; i < 16; i++) {
#pragma unroll
        for (int j = 0; j < 16; j++) o[j] = fmaf(a[i], w2[i * 16 + j], o[j]);
    }
#pragma unroll
    for (int j = 0; j < 16; j++) h[v * 16 + j] = o[j];
}

// ---------------- edge geometry + RBF + edge MLP (32->16->16) + dst count ----------------
__global__ __launch_bounds__(256) void k_edge_geom(const int* __restrict__ eir, const int* __restrict__ eip,
                                                   const float* __restrict__ posr, const float* __restrict__ posp,
                                                   float* __restrict__ sh1d, float* __restrict__ eemb,
                                                   float* __restrict__ cnt,
                                                   const float* __restrict__ w1, const float* __restrict__ b1,
                                                   const float* __restrict__ w2, const float* __restrict__ b2) {
    int mol = blockIdx.y;
    const int* ei = mol ? eip : eir;
    const float* pos = mol ? posp : posr;
    float* sh_ = sh1d + (size_t)mol * NE * 4;
    float* em_ = eemb + (size_t)mol * NE * 16;
    float* cn_ = cnt + (size_t)mol * NN;
    int e = blockIdx.x * 256 + threadIdx.x;
    int s = ei[e], d = ei[NE + e];
    float ex = pos[d * 3 + 0] - pos[s * 3 + 0];
    float ey = pos[d * 3 + 1] - pos[s * 3 + 1];
    float ez = pos[d * 3 + 2] - pos[s * 3 + 2];
    float dist = sqrtf(ex * ex + ey * ey + ez * ez + 1e-12f);
    float inv = SQRT3F / dist;
    sh_[e * 4 + 0] = ex * inv;
    sh_[e * 4 + 1] = ey * inv;
    sh_[e * 4 + 2] = ez * inv;
    sh_[e * 4 + 3] = dist;
    float g[32];
#pragma unroll
    for (int i = 0; i < 32; i++) {
        float t = dist - (float)i * GSTEP;
        g[i] = __expf(GCOEFF * t * t);
    }
    float a[16];
#pragma unroll
    for (int j = 0; j < 16; j++) a[j] = b1[j];
#pragma unroll
    for (int i = 0; i < 32; i++) {
#pragma unroll
        for (int j = 0; j < 16; j++) a[j] = fmaf(g[i], w1[i * 16 + j], a[j]);
    }
#pragma unroll
    for (int j = 0; j < 16; j++) a[j] = fmaxf(a[j], 0.f);
    float o[16];
#pragma unroll
    for (int j = 0; j < 16; j++) o[j] = b2[j];
#pragma unroll
    for (int i = 0; i < 16; i++) {
#pragma unroll
        for (int j = 0; j < 16; j++) o[j] = fmaf(a[i], w2[i * 16 + j], o[j]);
    }
#pragma unroll
    for (int j = 0; j < 16; j++) em_[e * 16 + j] = o[j];
    atomicAdd(&cn_[d], 1.0f);
}

// ---------------- conv0: per edge, ea(48)->hid(48)->w(512) fused with TP, atomic scatter ----------------
__global__ __launch_bounds__(256) void k_conv0(const int* __restrict__ eir, const int* __restrict__ eip,
                                               const float* __restrict__ eemb, const float* __restrict__ h16,
                                               const float* __restrict__ sh1d,
                                               const float* __restrict__ b1, const float* __restrict__ w1,
                                               const float* __restrict__ w2t, const float* __restrict__ b2,
                                               float* __restrict__ up0) {
    __shared__ float lds[256 * 49];
    int mol = blockIdx.y;
    const int* ei = mol ? eip : eir;
    const float* em_ = eemb + (size_t)mol * NE * 16;
    const float* h_ = h16 + (size_t)mol * NN * 16;
    const float* sh_ = sh1d + (size_t)mol * NE * 4;
    float* up_ = up0 + (size_t)mol * NN * 64;
    int tid = threadIdx.x;
    int e = blockIdx.x * 256 + tid;
    int s = ei[e], d = ei[NE + e];
    float* ea = &lds[tid * 49];
#pragma unroll
    for (int i = 0; i < 16; i++) ea[i] = em_[e * 16 + i];
#pragma unroll
    for (int i = 0; i < 16; i++) ea[16 + i] = h_[d * 16 + i];
#pragma unroll
    for (int i = 0; i < 16; i++) ea[32 + i] = h_[s * 16 + i];
    float hid[48];
#pragma unroll
    for (int j = 0; j < 48; j++) hid[j] = b1[j];
#pragma unroll 4
    for (int i = 0; i < 48; i++) {
        float v = ea[i];
#pragma unroll
        for (int j = 0; j < 48; j++) hid[j] = fmaf(v, w1[i * 48 + j], hid[j]);
    }
#pragma unroll
    for (int j = 0; j < 48; j++) hid[j] = fmaxf(hid[j], 0.f);
    float o0[16], t1[16];
#pragma unroll
    for (int w = 0; w < 16; w++) { o0[w] = 0.f; t1[w] = 0.f; }
#pragma unroll 1
    for (int u = 0; u < 16; u++) {
        float xu = ea[32 + u];
#pragma unroll
        for (int w = 0; w < 16; w++) {
            int k0 = u * 16 + w;
            float a0 = b2[k0];
            float a1 = b2[256 + k0];
            const float* r0 = &w2t[k0 * 48];
            const float* r1 = &w2t[(256 + k0) * 48];
#pragma unroll
            for (int h = 0; h < 48; h++) a0 = fmaf(hid[h], r0[h], a0);
#pragma unroll
            for (int h = 0; h < 48; h++) a1 = fmaf(hid[h], r1[h], a1);
            o0[w] = fmaf(xu, a0, o0[w]);
            t1[w] = fmaf(xu, a1, t1[w]);
        }
    }
    float s0 = sh_[e * 4 + 0], s1 = sh_[e * 4 + 1], s2 = sh_[e * 4 + 2];
    float* ud = up_ + (size_t)d * 64;
#pragma unroll
    for (int w = 0; w < 16; w++) atomicAdd(&ud[w], 0.25f * o0[w]);
#pragma unroll
    for (int w = 0; w < 16; w++) {
        float t = 0.25f * t1[w];
        atomicAdd(&ud[16 + w * 3 + 0], t * s0);
        atomicAdd(&ud[16 + w * 3 + 1], t * s1);
        atomicAdd(&ud[16 + w * 3 + 2], t * s2);
    }
}

// ---------------- h64 = pad(h16) + up0 / max(cnt,1) ----------------
__global__ __launch_bounds__(256) void k_up0(const float* __restrict__ h16, const float* __restrict__ up0,
                                             const float* __restrict__ cnt, float* __restrict__ h64) {
    int mol = blockIdx.y;
    const float* h_ = h16 + (size_t)mol * NN * 16;
    const float* u_ = up0 + (size_t)mol * NN * 64;
    const float* c_ = cnt + (size_t)mol * NN;
    float* o_ = h64 + (size_t)mol * NN * 64;
    int v = blockIdx.x * 256 + threadIdx.x;
    float rc = 1.0f / fmaxf(c_[v], 1.0f);
#pragma unroll
    for (int c = 0; c < 64; c++) {
        float base = (c < 16) ? h_[v * 16 + c] : 0.f;
        o_[v * 64 + c] = fmaf(u_[v * 64 + c], rc, base);
    }
}

// ---------------- conv1 pass 1: blocks A(0), B(256), D(768) -> o0(16) + o1o_B(48) ----------------
__global__ __launch_bounds__(256) void k_conv1a(const int* __restrict__ eir, const int* __restrict__ eip,
                                                const float* __restrict__ eemb, const float* __restrict__ h64,
                                                const float* __restrict__ sh1d,
                                                const float* __restrict__ b1, const float* __restrict__ w1,
                                                const float* __restrict__ w2t, const float* __restrict__ b2,
                                                float* __restrict__ up1) {
    __shared__ float lds[256 * 49];
    int mol = blockIdx.y;
    const int* ei = mol ? eip : eir;
    const float* em_ = eemb + (size_t)mol * NE * 16;
    const float* h_ = h64 + (size_t)mol * NN * 64;
    const float* sh_ = sh1d + (size_t)mol * NE * 4;
    float* up_ = up1 + (size_t)mol * NN * 112;
    int tid = threadIdx.x;
    int e = blockIdx.x * 256 + tid;
    int s = ei[e], d = ei[NE + e];
    float* ea = &lds[tid * 49];
#pragma unroll
    for (int i = 0; i < 16; i++) ea[i] = em_[e * 16 + i];
#pragma unroll
    for (int i = 0; i < 16; i++) ea[16 + i] = h_[d * 64 + i];
#pragma unroll
    for (int i = 0; i < 16; i++) ea[32 + i] = h_[s * 64 + i];
    float hid[48];
#pragma unroll
    for (int j = 0; j < 48; j++) hid[j] = b1[j];
#pragma unroll 4
    for (int i = 0; i < 48; i++) {
        float v = ea[i];
#pragma unroll
        for (int j = 0; j < 48; j++) hid[j] = fmaf(v, w1[i * 48 + j], hid[j]);
    }
#pragma unroll
    for (int j = 0; j < 48; j++) hid[j] = fmaxf(hid[j], 0.f);
    float s0 = sh_[e * 4 + 0], s1 = sh_[e * 4 + 1], s2 = sh_[e * 4 + 2];
    float o0[16], tB[16];
#pragma unroll
    for (int w = 0; w < 16; w++) { o0[w] = 0.f; tB[w] = 0.f; }
#pragma unroll 1
    for (int u = 0; u < 16; u++) {
        float xu = ea[32 + u];
        float x10 = h_[s * 64 + 16 + u * 3 + 0];
        float x11 = h_[s * 64 + 16 + u * 3 + 1];
        float x12 = h_[s * 64 + 16 + u * 3 + 2];
        float du = fmaf(x10, s0, fmaf(x11, s1, x12 * s2)) * (1.0f / SQRT3F);
#pragma unroll
        for (int w = 0; w < 16; w++) {
            int k = u * 16 + w;
            float a = b2[k];
            float bb = b2[256 + k];
            float dd = b2[768 + k];
            const float* ra = &w2t[k * 48];
            const float* rb = &w2t[(256 + k) * 48];
            const float* rd = &w2t[(768 + k) * 48];
#pragma unroll
            for (int h = 0; h < 48; h++) a = fmaf(hid[h], ra[h], a);
#pragma unroll
            for (int h = 0; h < 48; h++) bb = fmaf(hid[h], rb[h], bb);
#pragma unroll
            for (int h = 0; h < 48; h++) dd = fmaf(hid[h], rd[h], dd);
            o0[w] = fmaf(xu, a, o0[w]);
            tB[w] = fmaf(xu, bb, tB[w]);
            o0[w] = fmaf(du, dd, o0[w]);
        }
    }
    float* ud = up_ + (size_t)d * 112;
#pragma unroll
    for (int w = 0; w < 16; w++) atomicAdd(&ud[w], PW * o0[w]);
#pragma unroll
    for (int w = 0; w < 16; w++) {
        float t = PW * tB[w];
        atomicAdd(&ud[16 + w * 3 + 0], t * s0);
        atomicAdd(&ud[16 + w * 3 + 1], t * s1);
        atomicAdd(&ud[16 + w * 3 + 2], t * s2);
    }
}

// ---------------- conv1 pass 2: blocks C(512), E(1024) -> o1o_C(48) + o1e(48) ----------------
__global__ __launch_bounds__(256) void k_conv1b(const int* __restrict__ eir, const int* __restrict__ eip,
                                                const float* __restrict__ eemb, const float* __restrict__ h64,
                                                const float* __restrict__ sh1d,
                                                const float* __restrict__ b1, const float* __restrict__ w1,
                                                const float* __restrict__ w2t, const float* __restrict__ b2,
                                                float* __restrict__ up1) {
    __shared__ float lds[256 * 49];
    int mol = blockIdx.y;
    const int* ei = mol ? eip : eir;
    const float* em_ = eemb + (size_t)mol * NE * 16;
    const float* h_ = h64 + (size_t)mol * NN * 64;
    const float* sh_ = sh1d + (size_t)mol * NE * 4;
    float* up_ = up1 + (size_t)mol * NN * 112;
    int tid = threadIdx.x;
    int e = blockIdx.x * 256 + tid;
    int s = ei[e], d = ei[NE + e];
    float* ea = &lds[tid * 49];
#pragma unroll
    for (int i = 0; i < 16; i++) ea[i] = em_[e * 16 + i];
#pragma unroll
    for (int i = 0; i < 16; i++) ea[16 + i] = h_[d * 64 + i];
#pragma unroll
    for (int i = 0; i < 16; i++) ea[32 + i] = h_[s * 64 + i];
    float hid[48];
#pragma unroll
    for (int j = 0; j < 48; j++) hid[j] = b1[j];
#pragma unroll 4
    for (int i = 0; i < 48; i++) {
        float v = ea[i];
#pragma unroll
        for (int j = 0; j < 48; j++) hid[j] = fmaf(v, w1[i * 48 + j], hid[j]);
    }
#pragma unroll
    for (int j = 0; j < 48; j++) hid[j] = fmaxf(hid[j], 0.f);
    float s0 = sh_[e * 4 + 0], s1 = sh_[e * 4 + 1], s2 = sh_[e * 4 + 2];
    float oc[48], oe[48];
#pragma unroll
    for (int w = 0; w < 48; w++) { oc[w] = 0.f; oe[w] = 0.f; }
#pragma unroll 1
    for (int u = 0; u < 16; u++) {
        float x10 = h_[s * 64 + 16 + u * 3 + 0];
        float x11 = h_[s * 64 + 16 + u * 3 + 1];
        float x12 = h_[s * 64 + 16 + u * 3 + 2];
        float cr0 = x11 * s2 - x12 * s1;
        float cr1 = x12 * s0 - x10 * s2;
        float cr2 = x10 * s1 - x11 * s0;
#pragma unroll
        for (int w = 0; w < 16; w++) {
            int k = u * 16 + w;
            float c = b2[512 + k];
            float ev = b2[1024 + k];
            const float* rc_ = &w2t[(512 + k) * 48];
            const float* re_ = &w2t[(1024 + k) * 48];
#pragma unroll
            for (int h = 0; h < 48; h++) c = fmaf(hid[h], rc_[h], c);
#pragma unroll
            for (int h = 0; h < 48; h++) ev = fmaf(hid[h], re_[h], ev);
            oc[w * 3 + 0] = fmaf(x10, c, oc[w * 3 + 0]);
            oc[w * 3 + 1] = fmaf(x11, c, oc[w * 3 + 1]);
            oc[w * 3 + 2] = fmaf(x12, c, oc[w * 3 + 2]);
            oe[w * 3 + 0] = fmaf(cr0, ev, oe[w * 3 + 0]);
            oe[w * 3 + 1] = fmaf(cr1, ev, oe[w * 3 + 1]);
            oe[w * 3 + 2] = fmaf(cr2, ev, oe[w * 3 + 2]);
        }
    }
    float* ud = up_ + (size_t)d * 112;
#pragma unroll
    for (int w = 0; w < 48; w++) atomicAdd(&ud[16 + w], PW * oc[w]);
#pragma unroll
    for (int w = 0; w < 48; w++) atomicAdd(&ud[64 + w], PW * oe[w]);
}

// ---------------- xf = h64[:16] + up1[:16]/cnt; s_nodes MLP; bucket into out ----------------
__global__ __launch_bounds__(256) void k_xf_snode(const float* __restrict__ h64, const float* __restrict__ up1,
                                                  const float* __restrict__ cnt, float* __restrict__ xf,
                                                  const int* __restrict__ batchr, const int* __restrict__ batchp,
                                                  const float* __restrict__ w1, const float* __restrict__ b1,
                                                  const float* __restrict__ w2, const float* __restrict__ b2,
                                                  const float* __restrict__ w3, const float* __restrict__ b3,
                                                  float* __restrict__ out) {
    __shared__ float buck[64];
    int tid = threadIdx.x;
    if (tid < 64) buck[tid] = 0.f;
    __syncthreads();
    int mol = blockIdx.y;
    float sign = mol ? 1.f : -1.f;
    const int* batch = mol ? batchp : batchr;
    const float* h_ = h64 + (size_t)mol * NN * 64;
    const float* u_ = up1 + (size_t)mol * NN * 112;
    const float* c_ = cnt + (size_t)mol * NN;
    float* xf_ = xf + (size_t)mol * NN * 16;
    int v = blockIdx.x * 256 + tid;
    float rc = 1.0f / fmaxf(c_[v], 1.0f);
    float xv[16];
#pragma unroll
    for (int c = 0; c < 16; c++) {
        xv[c] = fmaf(u_[v * 112 + c], rc, h_[v * 64 + c]);
        xf_[v * 16 + c] = xv[c];
    }
    float a[32];
#pragma unroll
    for (int j = 0; j < 32; j++) a[j] = b1[j];
#pragma unroll
    for (int i = 0; i < 16; i++) {
#pragma unroll
        for (int j = 0; j < 32; j++) a[j] = fmaf(xv[i], w1[i * 32 + j], a[j]);
    }
#pragma unroll
    for (int j = 0; j < 32; j++) a[j] = fmaxf(a[j], 0.f);
    float bb[16];
#pragma unroll
    for (int j = 0; j < 16; j++) bb[j] = b2[j];
#pragma unroll
    for (int i = 0; i < 32; i++) {
#pragma unroll
        for (int j = 0; j < 16; j++) bb[j] = fmaf(a[i], w2[i * 16 + j], bb[j]);
    }
#pragma unroll
    for (int j = 0; j < 16; j++) bb[j] = fmaxf(bb[j], 0.f);
    float val = b3[0];
#pragma unroll
    for (int i = 0; i < 16; i++) val = fmaf(bb[i], w3[i], val);
    atomicAdd(&buck[batch[v]], val);
    __syncthreads();
    if (tid < 64) atomicAdd(&out[tid], sign * buck[tid]);
}

// ---------------- s_edges MLP (64->16->16->1), bucket by batch[src] into out ----------------
__global__ __launch_bounds__(256) void k_sedge(const int* __restrict__ eir, const int* __restrict__ eip,
                                               const int* __restrict__ batchr, const int* __restrict__ batchp,
                                               const float* __restrict__ sh1d, const float* __restrict__ xf,
                                               const float* __restrict__ w1, const float* __restrict__ b1,
                                               const float* __restrict__ w2, const float* __restrict__ b2,
                                               const float* __restrict__ w3, const float* __restrict__ b3,
                                               float* __restrict__ out) {
    __shared__ float buck[64];
    int tid = threadIdx.x;
    if (tid < 64) buck[tid] = 0.f;
    __syncthreads();
    int mol = blockIdx.y;
    float sign = mol ? 1.f : -1.f;
    const int* ei = mol ? eip : eir;
    const int* batch = mol ? batchp : batchr;
    const float* sh_ = sh1d + (size_t)mol * NE * 4;
    const float* xf_ = xf + (size_t)mol * NN * 16;
    int e = blockIdx.x * 256 + tid;
    int s = ei[e], d = ei[NE + e];
    float dist = sh_[e * 4 + 3];
    float in[64];
#pragma unroll
    for (int i = 0; i < 32; i++) {
        float t = dist - (float)i * GSTEP;
        in[i] = __expf(GCOEFF * t * t);
    }
#pragma unroll
    for (int i = 0; i < 16; i++) in[32 + i] = xf_[s * 16 + i];
#pragma unroll
    for (int i = 0; i < 16; i++) in[48 + i] = xf_[d * 16 + i];
    float a[16];
#pragma unroll
    for (int j = 0; j < 16; j++) a[j] = b1[j];
#pragma unroll
    for (int i = 0; i < 64; i++) {
#pragma unroll
        for (int j = 0; j < 16; j++) a[j] = fmaf(in[i], w1[i * 16 + j], a[j]);
    }
#pragma unroll
    for (int j = 0; j < 16; j++) a[j] = fmaxf(a[j], 0.f);
    float bb[16];
#pragma unroll
    for (int j = 0; j < 16; j++) bb[j] = b2[j];
#pragma unroll
    for (int i = 0; i < 16; i++) {
#pragma unroll
        for (int j = 0; j < 16; j++) bb[j] = fmaf(a[i], w2[i * 16 + j], bb[j]);
    }
#pragma unroll
    for (int j = 0; j < 16; j++) bb[j] = fmaxf(bb[j], 0.f);
    float val = b3[0];
#pragma unroll
    for (int i = 0; i < 16; i++) val = fmaf(bb[i], w3[i], val);
    atomicAdd(&buck[batch[s]], val);
    __syncthreads();
    if (tid < 64) atomicAdd(&out[tid], sign * buck[tid]);
}

extern "C" void kernel_launch(void* const* d_in, const int* in_sizes, int n_in,
                              void* d_out, int out_size, void* d_ws, size_t ws_size,
                              hipStream_t stream) {
    const float* x_r = (const float*)d_in[0];
    const float* pos_r = (const float*)d_in[1];
    const int* ei_r = (const int*)d_in[2];
    const int* batch_r = (const int*)d_in[3];
    const float* x_p = (const float*)d_in[4];
    const float* pos_p = (const float*)d_in[5];
    const int* ei_p = (const int*)d_in[6];
    const int* batch_p = (const int*)d_in[7];
    const float* ne_w1 = (const float*)d_in[8];
    const float* ne_b1 = (const float*)d_in[9];
    const float* ne_w2 = (const float*)d_in[10];
    const float* ne_b2 = (const float*)d_in[11];
    const float* ee_w1 = (const float*)d_in[12];
    const float* ee_b1 = (const float*)d_in[13];
    const float* ee_w2 = (const float*)d_in[14];
    const float* ee_b2 = (const float*)d_in[15];
    const float* c0_w1 = (const float*)d_in[16];
    const float* c0_b1 = (const float*)d_in[17];
    const float* c0_w2 = (const float*)d_in[18];
    const float* c0_b2 = (const float*)d_in[19];
    const float* c1_w1 = (const float*)d_in[20];
    const float* c1_b1 = (const float*)d_in[21];
    const float* c1_w2 = (const float*)d_in[22];
    const float* c1_b2 = (const float*)d_in[23];
    const float* sn_w1 = (const float*)d_in[24];
    const float* sn_b1 = (const float*)d_in[25];
    const float* sn_w2 = (const float*)d_in[26];
    const float* sn_b2 = (const float*)d_in[27];
    const float* sn_w3 = (const float*)d_in[28];
    const float* sn_b3 = (const float*)d_in[29];
    const float* se_w1 = (const float*)d_in[30];
    const float* se_b1 = (const float*)d_in[31];
    const float* se_w2 = (const float*)d_in[32];
    const float* se_b2 = (const float*)d_in[33];
    const float* se_w3 = (const float*)d_in[34];
    const float* se_b3 = (const float*)d_in[35];
    float* out = (float*)d_out;
    float* ws = (float*)d_ws;

    size_t off = 0;
    float* w2t0 = ws + off; off += (size_t)512 * 48;
    float* w2t1 = ws + off; off += (size_t)1280 * 48;
    float* h16  = ws + off; off += (size_t)2 * NN * 16;
    float* sh1d = ws + off; off += (size_t)2 * NE * 4;
    float* eemb = ws + off; off += (size_t)2 * NE * 16;
    float* cnt  = ws + off; off += (size_t)2 * NN;
    float* up0  = ws + off; off += (size_t)2 * NN * 64;
    float* h64  = ws + off; off += (size_t)2 * NN * 64;
    float* up1  = ws + off; off += (size_t)2 * NN * 112;
    float* xf   = ws + off; off += (size_t)2 * NN * 16;
    (void)ws_size; (void)n_in; (void)in_sizes; (void)out_size;

    hipMemsetAsync(up0, 0, (size_t)2 * NN * 64 * 4, stream);
    hipMemsetAsync(up1, 0, (size_t)2 * NN * 112 * 4, stream);
    hipMemsetAsync(cnt, 0, (size_t)2 * NN * 4, stream);
    hipMemsetAsync(out, 0, 64 * 4, stream);

    dim3 blk(256, 1, 1);
    dim3 gn(NN / 256, 2, 1);   // node kernels, both molecules
    dim3 ge(NE / 256, 2, 1);   // edge kernels, both molecules

    k_transpose<<<dim3(240, 1, 1), blk, 0, stream>>>(c0_w2, w2t0, c1_w2, w2t1);
    k_node_mlp<<<gn, blk, 0, stream>>>(x_r, x_p, h16, ne_w1, ne_b1, ne_w2, ne_b2);
    k_edge_geom<<<ge, blk, 0, stream>>>(ei_r, ei_p, pos_r, pos_p, sh1d, eemb, cnt,
                                        ee_w1, ee_b1, ee_w2, ee_b2);
    k_conv0<<<ge, blk, 0, stream>>>(ei_r, ei_p, eemb, h16, sh1d, c0_b1, c0_w1, w2t0, c0_b2, up0);
    k_up0<<<gn, blk, 0, stream>>>(h16, up0, cnt, h64);
    k_conv1a<<<ge, blk, 0, stream>>>(ei_r, ei_p, eemb, h64, sh1d, c1_b1, c1_w1, w2t1, c1_b2, up1);
    k_conv1b<<<ge, blk, 0, stream>>>(ei_r, ei_p, eemb, h64, sh1d, c1_b1, c1_w1, w2t1, c1_b2, up1);
    k_xf_snode<<<gn, blk, 0, stream>>>(h64, up1, cnt, xf, batch_r, batch_p,
                                       sn_w1, sn_b1, sn_w2, sn_b2, sn_w3, sn_b3, out);
    k_sedge<<<ge, blk, 0, stream>>>(ei_r, ei_p, batch_r, batch_p, sh1d, xf,
                                    se_w1, se_b1, se_w2, se_b2, se_w3, se_b3, out);
}

// Round 2
// 2553.739 us; speedup vs baseline: 1.1402x; 1.1402x over previous
//
#include <hip/hip_runtime.h>
#include <math.h>

#define NN 8192
#define NE 65536
#define SQRT3F 1.7320508075688772f
#define INV_SQRT3F 0.5773502691896258f
#define PW 0.17677669529663687f      // 1/sqrt(32) == 0.25/sqrt(2)
#define GSTEP (10.0f/31.0f)
#define GCOEFF (-0.5f/(GSTEP*GSTEP))

// ---------------- transpose c0_w2 (48x512 -> 512x48), c1_w2 (48x1280 -> 1280x48) ----------------
__global__ __launch_bounds__(256) void k_transpose(const float* __restrict__ w0, float* __restrict__ w0t,
                                                   const float* __restrict__ w1, float* __restrict__ w1t) {
    int idx = blockIdx.x * 256 + threadIdx.x;          // grid covers 61440
    if (idx < 48 * 512) {
        int h = idx >> 9, k = idx & 511;
        w0t[k * 48 + h] = w0[idx];
    }
    if (idx < 48 * 1280) {
        int h = idx / 1280, k = idx - h * 1280;
        w1t[k * 48 + h] = w1[idx];
    }
}

// ---------------- node MLP: x(32) -> 16 -> 16 ----------------
__global__ __launch_bounds__(256) void k_node_mlp(const float* __restrict__ xr, const float* __restrict__ xp,
                                                  float* __restrict__ h16,
                                                  const float* __restrict__ w1, const float* __restrict__ b1,
                                                  const float* __restrict__ w2, const float* __restrict__ b2) {
    int mol = blockIdx.y;
    const float* x = mol ? xp : xr;
    float* h = h16 + (size_t)mol * NN * 16;
    int v = blockIdx.x * 256 + threadIdx.x;
    float xi[32];
#pragma unroll
    for (int i = 0; i < 32; i++) xi[i] = x[v * 32 + i];
    float a[16];
#pragma unroll
    for (int j = 0; j < 16; j++) a[j] = b1[j];
#pragma unroll
    for (int i = 0; i < 32; i++) {
#pragma unroll
        for (int j = 0; j < 16; j++) a[j] = fmaf(xi[i], w1[i * 16 + j], a[j]);
    }
#pragma unroll
    for (int j = 0; j < 16; j++) a[j] = fmaxf(a[j], 0.f);
    float o[16];
#pragma unroll
    for (int j = 0; j < 16; j++) o[j] = b2[j];
#pragma unroll
    for (int i = 0; i < 16; i++) {
#pragma unroll
        for (int j = 0; j < 16; j++) o[j] = fmaf(a[i], w2[i * 16 + j], o[j]);
    }
#pragma unroll
    for (int j = 0; j < 16; j++) h[v * 16 + j] = o[j];
}

// ---------------- edge geometry + RBF + edge MLP (32->16->16) + dst count ----------------
__global__ __launch_bounds__(256) void k_edge_geom(const int* __restrict__ eir, const int* __restrict__ eip,
                                                   const float* __restrict__ posr, const float* __restrict__ posp,
                                                   float* __restrict__ sh1d, float* __restrict__ eemb,
                                                   float* __restrict__ cnt,
                                                   const float* __restrict__ w1, const float* __restrict__ b1,
                                                   const float* __restrict__ w2, const float* __restrict__ b2) {
    int mol = blockIdx.y;
    const int* ei = mol ? eip : eir;
    const float* pos = mol ? posp : posr;
    float* sh_ = sh1d + (size_t)mol * NE * 4;
    float* em_ = eemb + (size_t)mol * NE * 16;
    float* cn_ = cnt + (size_t)mol * NN;
    int e = blockIdx.x * 256 + threadIdx.x;
    int s = ei[e], d = ei[NE + e];
    float ex = pos[d * 3 + 0] - pos[s * 3 + 0];
    float ey = pos[d * 3 + 1] - pos[s * 3 + 1];
    float ez = pos[d * 3 + 2] - pos[s * 3 + 2];
    float dist = sqrtf(ex * ex + ey * ey + ez * ez + 1e-12f);
    float inv = SQRT3F / dist;
    sh_[e * 4 + 0] = ex * inv;
    sh_[e * 4 + 1] = ey * inv;
    sh_[e * 4 + 2] = ez * inv;
    sh_[e * 4 + 3] = dist;
    float g[32];
#pragma unroll
    for (int i = 0; i < 32; i++) {
        float t = dist - (float)i * GSTEP;
        g[i] = __expf(GCOEFF * t * t);
    }
    float a[16];
#pragma unroll
    for (int j = 0; j < 16; j++) a[j] = b1[j];
#pragma unroll
    for (int i = 0; i < 32; i++) {
#pragma unroll
        for (int j = 0; j < 16; j++) a[j] = fmaf(g[i], w1[i * 16 + j], a[j]);
    }
#pragma unroll
    for (int j = 0; j < 16; j++) a[j] = fmaxf(a[j], 0.f);
    float o[16];
#pragma unroll
    for (int j = 0; j < 16; j++) o[j] = b2[j];
#pragma unroll
    for (int i = 0; i < 16; i++) {
#pragma unroll
        for (int j = 0; j < 16; j++) o[j] = fmaf(a[i], w2[i * 16 + j], o[j]);
    }
#pragma unroll
    for (int j = 0; j < 16; j++) em_[e * 16 + j] = o[j];
    atomicAdd(&cn_[d], 1.0f);
}

// helper macro: load 16 contiguous floats into 16 named registers via float4
#define LOAD16(dst, base, src) { \
    const float4* p_ = (const float4*)(src); \
    float4 t0_ = p_[0], t1_ = p_[1], t2_ = p_[2], t3_ = p_[3]; \
    dst[(base)+0]=t0_.x; dst[(base)+1]=t0_.y; dst[(base)+2]=t0_.z; dst[(base)+3]=t0_.w; \
    dst[(base)+4]=t1_.x; dst[(base)+5]=t1_.y; dst[(base)+6]=t1_.z; dst[(base)+7]=t1_.w; \
    dst[(base)+8]=t2_.x; dst[(base)+9]=t2_.y; dst[(base)+10]=t2_.z; dst[(base)+11]=t2_.w; \
    dst[(base)+12]=t3_.x; dst[(base)+13]=t3_.y; dst[(base)+14]=t3_.z; dst[(base)+15]=t3_.w; }

// hid-gen from eav[48] registers + w1s LDS (48x48 + b1 at 2304)
#define HIDGEN(hid, eav, w1s) { \
    _Pragma("unroll") \
    for (int q = 0; q < 12; q++) { \
        float4 bv = ((const float4*)&w1s[2304])[q]; \
        hid[q*4+0]=bv.x; hid[q*4+1]=bv.y; hid[q*4+2]=bv.z; hid[q*4+3]=bv.w; } \
    _Pragma("unroll") \
    for (int i = 0; i < 48; i++) { \
        float v_ = eav[i]; \
        const float4* row_ = (const float4*)&w1s[i*48]; \
        _Pragma("unroll") \
        for (int q = 0; q < 12; q++) { \
            float4 wv_ = row_[q]; \
            hid[q*4+0]=fmaf(v_,wv_.x,hid[q*4+0]); \
            hid[q*4+1]=fmaf(v_,wv_.y,hid[q*4+1]); \
            hid[q*4+2]=fmaf(v_,wv_.z,hid[q*4+2]); \
            hid[q*4+3]=fmaf(v_,wv_.w,hid[q*4+3]); } } \
    _Pragma("unroll") \
    for (int j = 0; j < 48; j++) hid[j] = fmaxf(hid[j], 0.f); }

// ---------------- conv0: ea(48)->hid(48); per-u LDS-staged weights; TP; atomic scatter ----------------
__global__ __launch_bounds__(256) void k_conv0(const int* __restrict__ eir, const int* __restrict__ eip,
                                               const float* __restrict__ eemb, const float* __restrict__ h16,
                                               const float* __restrict__ sh1d,
                                               const float* __restrict__ b1, const float* __restrict__ w1,
                                               const float* __restrict__ w2t, const float* __restrict__ b2,
                                               float* __restrict__ up0) {
    __shared__ __align__(16) float w1s[48*48 + 48];
    __shared__ __align__(16) float wbuf[2][2*768 + 32];
    int mol = blockIdx.y;
    const int* ei = mol ? eip : eir;
    const float* em_ = eemb + (size_t)mol * NE * 16;
    const float* h_ = h16 + (size_t)mol * NN * 16;
    const float* sh_ = sh1d + (size_t)mol * NE * 4;
    float* up_ = up0 + (size_t)mol * NN * 64;
    int tid = threadIdx.x;
    int e = blockIdx.x * 256 + tid;
    int s = ei[e], d = ei[NE + e];
#pragma unroll
    for (int r = 0; r < 9; r++) w1s[r*256 + tid] = w1[r*256 + tid];
    if (tid < 48) w1s[2304 + tid] = b1[tid];
    if (tid < 192) {
        ((float4*)&wbuf[0][0])[tid]   = ((const float4*)&w2t[0])[tid];
        ((float4*)&wbuf[0][768])[tid] = ((const float4*)&w2t[12288])[tid];
    }
    if (tid < 32) wbuf[0][1536 + tid] = b2[((tid>>4)<<8) + (tid & 15)];

    float eav[48];
    LOAD16(eav, 0,  &em_[(size_t)e*16]);
    LOAD16(eav, 16, &h_[(size_t)d*16]);
    LOAD16(eav, 32, &h_[(size_t)s*16]);
    __syncthreads();
    float hid[48];
    HIDGEN(hid, eav, w1s);

    float o0[16], t1[16];
#pragma unroll
    for (int w = 0; w < 16; w++) { o0[w] = 0.f; t1[w] = 0.f; }
#pragma unroll 1
    for (int u = 0; u < 16; ++u) {
        __syncthreads();
        if (u < 15) {
            int gb = (u + 1) * 768;
            int nb = (u + 1) & 1;
            if (tid < 192) {
                ((float4*)&wbuf[nb][0])[tid]   = ((const float4*)&w2t[gb])[tid];
                ((float4*)&wbuf[nb][768])[tid] = ((const float4*)&w2t[12288 + gb])[tid];
            }
            if (tid < 32) wbuf[nb][1536 + tid] = b2[((tid>>4)<<8) + (u+1)*16 + (tid & 15)];
        }
        const float* wb = wbuf[u & 1];
        float xu = h_[(size_t)s*16 + u];
#pragma unroll
        for (int w = 0; w < 16; w++) {
            float a0 = wb[1536 + w];
            float a1 = wb[1552 + w];
            const float4* r0 = (const float4*)&wb[w*48];
            const float4* r1 = (const float4*)&wb[768 + w*48];
#pragma unroll
            for (int q = 0; q < 12; q++) {
                float4 wa = r0[q], wbv = r1[q];
                a0 = fmaf(hid[q*4+0], wa.x, a0);
                a0 = fmaf(hid[q*4+1], wa.y, a0);
                a0 = fmaf(hid[q*4+2], wa.z, a0);
                a0 = fmaf(hid[q*4+3], wa.w, a0);
                a1 = fmaf(hid[q*4+0], wbv.x, a1);
                a1 = fmaf(hid[q*4+1], wbv.y, a1);
                a1 = fmaf(hid[q*4+2], wbv.z, a1);
                a1 = fmaf(hid[q*4+3], wbv.w, a1);
            }
            o0[w] = fmaf(xu, a0, o0[w]);
            t1[w] = fmaf(xu, a1, t1[w]);
        }
    }
    float s0 = sh_[e*4+0], s1 = sh_[e*4+1], s2 = sh_[e*4+2];
    float* ud = up_ + (size_t)d * 64;
#pragma unroll
    for (int w = 0; w < 16; w++) atomicAdd(&ud[w], 0.25f * o0[w]);
#pragma unroll
    for (int w = 0; w < 16; w++) {
        float t = 0.25f * t1[w];
        atomicAdd(&ud[16 + w*3 + 0], t * s0);
        atomicAdd(&ud[16 + w*3 + 1], t * s1);
        atomicAdd(&ud[16 + w*3 + 2], t * s2);
    }
}

// ---------------- h64 = pad(h16) + up0 / max(cnt,1) ----------------
__global__ __launch_bounds__(256) void k_up0(const float* __restrict__ h16, const float* __restrict__ up0,
                                             const float* __restrict__ cnt, float* __restrict__ h64) {
    int mol = blockIdx.y;
    const float* h_ = h16 + (size_t)mol * NN * 16;
    const float* u_ = up0 + (size_t)mol * NN * 64;
    const float* c_ = cnt + (size_t)mol * NN;
    float* o_ = h64 + (size_t)mol * NN * 64;
    int v = blockIdx.x * 256 + threadIdx.x;
    float rc = 1.0f / fmaxf(c_[v], 1.0f);
#pragma unroll
    for (int c = 0; c < 64; c++) {
        float base = (c < 16) ? h_[v * 16 + c] : 0.f;
        o_[v * 64 + c] = fmaf(u_[v * 64 + c], rc, base);
    }
}

// ---------------- conv1 pass 1: blocks A(0), B(256), D(768) -> o0(16) + o1o_B(48) ----------------
__global__ __launch_bounds__(256) void k_conv1a(const int* __restrict__ eir, const int* __restrict__ eip,
                                                const float* __restrict__ eemb, const float* __restrict__ h64,
                                                const float* __restrict__ sh1d,
                                                const float* __restrict__ b1, const float* __restrict__ w1,
                                                const float* __restrict__ w2t, const float* __restrict__ b2,
                                                float* __restrict__ up1) {
    __shared__ __align__(16) float w1s[48*48 + 48];
    __shared__ __align__(16) float wbuf[2][3*768 + 48];
    int mol = blockIdx.y;
    const int* ei = mol ? eip : eir;
    const float* em_ = eemb + (size_t)mol * NE * 16;
    const float* h_ = h64 + (size_t)mol * NN * 64;
    const float* sh_ = sh1d + (size_t)mol * NE * 4;
    float* up_ = up1 + (size_t)mol * NN * 112;
    int tid = threadIdx.x;
    int e = blockIdx.x * 256 + tid;
    int s = ei[e], d = ei[NE + e];
#pragma unroll
    for (int r = 0; r < 9; r++) w1s[r*256 + tid] = w1[r*256 + tid];
    if (tid < 48) w1s[2304 + tid] = b1[tid];
    if (tid < 192) {
        ((float4*)&wbuf[0][0])[tid]    = ((const float4*)&w2t[0])[tid];
        ((float4*)&wbuf[0][768])[tid]  = ((const float4*)&w2t[12288])[tid];
        ((float4*)&wbuf[0][1536])[tid] = ((const float4*)&w2t[36864])[tid];
    }
    if (tid < 48) {
        int m = tid >> 4;
        int moff = (m == 2) ? 768 : (m << 8);
        wbuf[0][2304 + tid] = b2[moff + (tid & 15)];
    }

    float eav[48];
    LOAD16(eav, 0,  &em_[(size_t)e*16]);
    LOAD16(eav, 16, &h_[(size_t)d*64]);
    LOAD16(eav, 32, &h_[(size_t)s*64]);
    __syncthreads();
    float hid[48];
    HIDGEN(hid, eav, w1s);

    float s0 = sh_[e*4+0], s1 = sh_[e*4+1], s2 = sh_[e*4+2];
    float o0[16], tB[16];
#pragma unroll
    for (int w = 0; w < 16; w++) { o0[w] = 0.f; tB[w] = 0.f; }
#pragma unroll 1
    for (int u = 0; u < 16; ++u) {
        __syncthreads();
        if (u < 15) {
            int gb = (u + 1) * 768;
            int nb = (u + 1) & 1;
            if (tid < 192) {
                ((float4*)&wbuf[nb][0])[tid]    = ((const float4*)&w2t[gb])[tid];
                ((float4*)&wbuf[nb][768])[tid]  = ((const float4*)&w2t[12288 + gb])[tid];
                ((float4*)&wbuf[nb][1536])[tid] = ((const float4*)&w2t[36864 + gb])[tid];
            }
            if (tid < 48) {
                int m = tid >> 4;
                int moff = (m == 2) ? 768 : (m << 8);
                wbuf[nb][2304 + tid] = b2[moff + (u+1)*16 + (tid & 15)];
            }
        }
        const float* wb = wbuf[u & 1];
        float xu  = h_[(size_t)s*64 + u];
        float x10 = h_[(size_t)s*64 + 16 + u*3 + 0];
        float x11 = h_[(size_t)s*64 + 16 + u*3 + 1];
        float x12 = h_[(size_t)s*64 + 16 + u*3 + 2];
        float du = fmaf(x10, s0, fmaf(x11, s1, x12 * s2)) * INV_SQRT3F;
#pragma unroll
        for (int w = 0; w < 16; w++) {
            float a  = wb[2304 + w];
            float bv = wb[2320 + w];
            float dd = wb[2336 + w];
            const float4* ra = (const float4*)&wb[w*48];
            const float4* rb = (const float4*)&wb[768 + w*48];
            const float4* rd = (const float4*)&wb[1536 + w*48];
#pragma unroll
            for (int q = 0; q < 12; q++) {
                float4 wa = ra[q], wbv = rb[q], wd = rd[q];
                a  = fmaf(hid[q*4+0], wa.x, a);
                a  = fmaf(hid[q*4+1], wa.y, a);
                a  = fmaf(hid[q*4+2], wa.z, a);
                a  = fmaf(hid[q*4+3], wa.w, a);
                bv = fmaf(hid[q*4+0], wbv.x, bv);
                bv = fmaf(hid[q*4+1], wbv.y, bv);
                bv = fmaf(hid[q*4+2], wbv.z, bv);
                bv = fmaf(hid[q*4+3], wbv.w, bv);
                dd = fmaf(hid[q*4+0], wd.x, dd);
                dd = fmaf(hid[q*4+1], wd.y, dd);
                dd = fmaf(hid[q*4+2], wd.z, dd);
                dd = fmaf(hid[q*4+3], wd.w, dd);
            }
            o0[w] = fmaf(xu, a, o0[w]);
            tB[w] = fmaf(xu, bv, tB[w]);
            o0[w] = fmaf(du, dd, o0[w]);
        }
    }
    float* ud = up_ + (size_t)d * 112;
#pragma unroll
    for (int w = 0; w < 16; w++) atomicAdd(&ud[w], PW * o0[w]);
#pragma unroll
    for (int w = 0; w < 16; w++) {
        float t = PW * tB[w];
        atomicAdd(&ud[16 + w*3 + 0], t * s0);
        atomicAdd(&ud[16 + w*3 + 1], t * s1);
        atomicAdd(&ud[16 + w*3 + 2], t * s2);
    }
}

// ---------------- conv1 pass 2: blocks C(512), E(1024) -> o1o_C(48) + o1e(48) ----------------
__global__ __launch_bounds__(256) void k_conv1b(const int* __restrict__ eir, const int* __restrict__ eip,
                                                const float* __restrict__ eemb, const float* __restrict__ h64,
                                                const float* __restrict__ sh1d,
                                                const float* __restrict__ b1, const float* __restrict__ w1,
                                                const float* __restrict__ w2t, const float* __restrict__ b2,
                                                float* __restrict__ up1) {
    __shared__ __align__(16) float w1s[48*48 + 48];
    __shared__ __align__(16) float wbuf[2][2*768 + 32];
    int mol = blockIdx.y;
    const int* ei = mol ? eip : eir;
    const float* em_ = eemb + (size_t)mol * NE * 16;
    const float* h_ = h64 + (size_t)mol * NN * 64;
    const float* sh_ = sh1d + (size_t)mol * NE * 4;
    float* up_ = up1 + (size_t)mol * NN * 112;
    int tid = threadIdx.x;
    int e = blockIdx.x * 256 + tid;
    int s = ei[e], d = ei[NE + e];
#pragma unroll
    for (int r = 0; r < 9; r++) w1s[r*256 + tid] = w1[r*256 + tid];
    if (tid < 48) w1s[2304 + tid] = b1[tid];
    if (tid < 192) {
        ((float4*)&wbuf[0][0])[tid]   = ((const float4*)&w2t[24576])[tid];
        ((float4*)&wbuf[0][768])[tid] = ((const float4*)&w2t[49152])[tid];
    }
    if (tid < 32) wbuf[0][1536 + tid] = b2[512 + ((tid>>4)<<9) + (tid & 15)];

    float eav[48];
    LOAD16(eav, 0,  &em_[(size_t)e*16]);
    LOAD16(eav, 16, &h_[(size_t)d*64]);
    LOAD16(eav, 32, &h_[(size_t)s*64]);
    __syncthreads();
    float hid[48];
    HIDGEN(hid, eav, w1s);

    float s0 = sh_[e*4+0], s1 = sh_[e*4+1], s2 = sh_[e*4+2];
    float oc[48], oe[48];
#pragma unroll
    for (int w = 0; w < 48; w++) { oc[w] = 0.f; oe[w] = 0.f; }
#pragma unroll 1
    for (int u = 0; u < 16; ++u) {
        __syncthreads();
        if (u < 15) {
            int gb = (u + 1) * 768;
            int nb = (u + 1) & 1;
            if (tid < 192) {
                ((float4*)&wbuf[nb][0])[tid]   = ((const float4*)&w2t[24576 + gb])[tid];
                ((float4*)&wbuf[nb][768])[tid] = ((const float4*)&w2t[49152 + gb])[tid];
            }
            if (tid < 32) wbuf[nb][1536 + tid] = b2[512 + ((tid>>4)<<9) + (u+1)*16 + (tid & 15)];
        }
        const float* wb = wbuf[u & 1];
        float x10 = h_[(size_t)s*64 + 16 + u*3 + 0];
        float x11 = h_[(size_t)s*64 + 16 + u*3 + 1];
        float x12 = h_[(size_t)s*64 + 16 + u*3 + 2];
        float cr0 = x11 * s2 - x12 * s1;
        float cr1 = x12 * s0 - x10 * s2;
        float cr2 = x10 * s1 - x11 * s0;
#pragma unroll
        for (int w = 0; w < 16; w++) {
            float c  = wb[1536 + w];
            float ev = wb[1552 + w];
            const float4* rc_ = (const float4*)&wb[w*48];
            const float4* re_ = (const float4*)&wb[768 + w*48];
#pragma unroll
            for (int q = 0; q < 12; q++) {
                float4 wc = rc_[q], we = re_[q];
                c  = fmaf(hid[q*4+0], wc.x, c);
                c  = fmaf(hid[q*4+1], wc.y, c);
                c  = fmaf(hid[q*4+2], wc.z, c);
                c  = fmaf(hid[q*4+3], wc.w, c);
                ev = fmaf(hid[q*4+0], we.x, ev);
                ev = fmaf(hid[q*4+1], we.y, ev);
                ev = fmaf(hid[q*4+2], we.z, ev);
                ev = fmaf(hid[q*4+3], we.w, ev);
            }
            oc[w*3+0] = fmaf(x10, c, oc[w*3+0]);
            oc[w*3+1] = fmaf(x11, c, oc[w*3+1]);
            oc[w*3+2] = fmaf(x12, c, oc[w*3+2]);
            oe[w*3+0] = fmaf(cr0, ev, oe[w*3+0]);
            oe[w*3+1] = fmaf(cr1, ev, oe[w*3+1]);
            oe[w*3+2] = fmaf(cr2, ev, oe[w*3+2]);
        }
    }
    float* ud = up_ + (size_t)d * 112;
#pragma unroll
    for (int w = 0; w < 48; w++) atomicAdd(&ud[16 + w], PW * oc[w]);
#pragma unroll
    for (int w = 0; w < 48; w++) atomicAdd(&ud[64 + w], PW * oe[w]);
}

// ---------------- xf = h64[:16] + up1[:16]/cnt; s_nodes MLP; bucket into out ----------------
__global__ __launch_bounds__(256) void k_xf_snode(const float* __restrict__ h64, const float* __restrict__ up1,
                                                  const float* __restrict__ cnt, float* __restrict__ xf,
                                                  const int* __restrict__ batchr, const int* __restrict__ batchp,
                                                  const float* __restrict__ w1, const float* __restrict__ b1,
                                                  const float* __restrict__ w2, const float* __restrict__ b2,
                                                  const float* __restrict__ w3, const float* __restrict__ b3,
                                                  float* __restrict__ out) {
    __shared__ float buck[64];
    int tid = threadIdx.x;
    if (tid < 64) buck[tid] = 0.f;
    __syncthreads();
    int mol = blockIdx.y;
    float sign = mol ? 1.f : -1.f;
    const int* batch = mol ? batchp : batchr;
    const float* h_ = h64 + (size_t)mol * NN * 64;
    const float* u_ = up1 + (size_t)mol * NN * 112;
    const float* c_ = cnt + (size_t)mol * NN;
    float* xf_ = xf + (size_t)mol * NN * 16;
    int v = blockIdx.x * 256 + tid;
    float rc = 1.0f / fmaxf(c_[v], 1.0f);
    float xv[16];
#pragma unroll
    for (int c = 0; c < 16; c++) {
        xv[c] = fmaf(u_[v * 112 + c], rc, h_[v * 64 + c]);
        xf_[v * 16 + c] = xv[c];
    }
    float a[32];
#pragma unroll
    for (int j = 0; j < 32; j++) a[j] = b1[j];
#pragma unroll
    for (int i = 0; i < 16; i++) {
#pragma unroll
        for (int j = 0; j < 32; j++) a[j] = fmaf(xv[i], w1[i * 32 + j], a[j]);
    }
#pragma unroll
    for (int j = 0; j < 32; j++) a[j] = fmaxf(a[j], 0.f);
    float bb[16];
#pragma unroll
    for (int j = 0; j < 16; j++) bb[j] = b2[j];
#pragma unroll
    for (int i = 0; i < 32; i++) {
#pragma unroll
        for (int j = 0; j < 16; j++) bb[j] = fmaf(a[i], w2[i * 16 + j], bb[j]);
    }
#pragma unroll
    for (int j = 0; j < 16; j++) bb[j] = fmaxf(bb[j], 0.f);
    float val = b3[0];
#pragma unroll
    for (int i = 0; i < 16; i++) val = fmaf(bb[i], w3[i], val);
    atomicAdd(&buck[batch[v]], val);
    __syncthreads();
    if (tid < 64) atomicAdd(&out[tid], sign * buck[tid]);
}

// ---------------- s_edges MLP (64->16->16->1), bucket by batch[src] into out ----------------
__global__ __launch_bounds__(256) void k_sedge(const int* __restrict__ eir, const int* __restrict__ eip,
                                               const int* __restrict__ batchr, const int* __restrict__ batchp,
                                               const float* __restrict__ sh1d, const float* __restrict__ xf,
                                               const float* __restrict__ w1, const float* __restrict__ b1,
                                               const float* __restrict__ w2, const float* __restrict__ b2,
                                               const float* __restrict__ w3, const float* __restrict__ b3,
                                               float* __restrict__ out) {
    __shared__ float buck[64];
    int tid = threadIdx.x;
    if (tid < 64) buck[tid] = 0.f;
    __syncthreads();
    int mol = blockIdx.y;
    float sign = mol ? 1.f : -1.f;
    const int* ei = mol ? eip : eir;
    const int* batch = mol ? batchp : batchr;
    const float* sh_ = sh1d + (size_t)mol * NE * 4;
    const float* xf_ = xf + (size_t)mol * NN * 16;
    int e = blockIdx.x * 256 + tid;
    int s = ei[e], d = ei[NE + e];
    float dist = sh_[e * 4 + 3];
    float in[64];
#pragma unroll
    for (int i = 0; i < 32; i++) {
        float t = dist - (float)i * GSTEP;
        in[i] = __expf(GCOEFF * t * t);
    }
#pragma unroll
    for (int i = 0; i < 16; i++) in[32 + i] = xf_[s * 16 + i];
#pragma unroll
    for (int i = 0; i < 16; i++) in[48 + i] = xf_[d * 16 + i];
    float a[16];
#pragma unroll
    for (int j = 0; j < 16; j++) a[j] = b1[j];
#pragma unroll
    for (int i = 0; i < 64; i++) {
#pragma unroll
        for (int j = 0; j < 16; j++) a[j] = fmaf(in[i], w1[i * 16 + j], a[j]);
    }
#pragma unroll
    for (int j = 0; j < 16; j++) a[j] = fmaxf(a[j], 0.f);
    float bb[16];
#pragma unroll
    for (int j = 0; j < 16; j++) bb[j] = b2[j];
#pragma unroll
    for (int i = 0; i < 16; i++) {
#pragma unroll
        for (int j = 0; j < 16; j++) bb[j] = fmaf(a[i], w2[i * 16 + j], bb[j]);
    }
#pragma unroll
    for (int j = 0; j < 16; j++) bb[j] = fmaxf(bb[j], 0.f);
    float val = b3[0];
#pragma unroll
    for (int i = 0; i < 16; i++) val = fmaf(bb[i], w3[i], val);
    atomicAdd(&buck[batch[s]], val);
    __syncthreads();
    if (tid < 64) atomicAdd(&out[tid], sign * buck[tid]);
}

extern "C" void kernel_launch(void* const* d_in, const int* in_sizes, int n_in,
                              void* d_out, int out_size, void* d_ws, size_t ws_size,
                              hipStream_t stream) {
    const float* x_r = (const float*)d_in[0];
    const float* pos_r = (const float*)d_in[1];
    const int* ei_r = (const int*)d_in[2];
    const int* batch_r = (const int*)d_in[3];
    const float* x_p = (const float*)d_in[4];
    const float* pos_p = (const float*)d_in[5];
    const int* ei_p = (const int*)d_in[6];
    const int* batch_p = (const int*)d_in[7];
    const float* ne_w1 = (const float*)d_in[8];
    const float* ne_b1 = (const float*)d_in[9];
    const float* ne_w2 = (const float*)d_in[10];
    const float* ne_b2 = (const float*)d_in[11];
    const float* ee_w1 = (const float*)d_in[12];
    const float* ee_b1 = (const float*)d_in[13];
    const float* ee_w2 = (const float*)d_in[14];
    const float* ee_b2 = (const float*)d_in[15];
    const float* c0_w1 = (const float*)d_in[16];
    const float* c0_b1 = (const float*)d_in[17];
    const float* c0_w2 = (const float*)d_in[18];
    const float* c0_b2 = (const float*)d_in[19];
    const float* c1_w1 = (const float*)d_in[20];
    const float* c1_b1 = (const float*)d_in[21];
    const float* c1_w2 = (const float*)d_in[22];
    const float* c1_b2 = (const float*)d_in[23];
    const float* sn_w1 = (const float*)d_in[24];
    const float* sn_b1 = (const float*)d_in[25];
    const float* sn_w2 = (const float*)d_in[26];
    const float* sn_b2 = (const float*)d_in[27];
    const float* sn_w3 = (const float*)d_in[28];
    const float* sn_b3 = (const float*)d_in[29];
    const float* se_w1 = (const float*)d_in[30];
    const float* se_b1 = (const float*)d_in[31];
    const float* se_w2 = (const float*)d_in[32];
    const float* se_b2 = (const float*)d_in[33];
    const float* se_w3 = (const float*)d_in[34];
    const float* se_b3 = (const float*)d_in[35];
    float* out = (float*)d_out;
    float* ws = (float*)d_ws;

    size_t off = 0;
    float* w2t0 = ws + off; off += (size_t)512 * 48;
    float* w2t1 = ws + off; off += (size_t)1280 * 48;
    float* h16  = ws + off; off += (size_t)2 * NN * 16;
    float* sh1d = ws + off; off += (size_t)2 * NE * 4;
    float* eemb = ws + off; off += (size_t)2 * NE * 16;
    float* cnt  = ws + off; off += (size_t)2 * NN;
    float* up0  = ws + off; off += (size_t)2 * NN * 64;
    float* h64  = ws + off; off += (size_t)2 * NN * 64;
    float* up1  = ws + off; off += (size_t)2 * NN * 112;
    float* xf   = ws + off; off += (size_t)2 * NN * 16;
    (void)ws_size; (void)n_in; (void)in_sizes; (void)out_size;

    hipMemsetAsync(up0, 0, (size_t)2 * NN * 64 * 4, stream);
    hipMemsetAsync(up1, 0, (size_t)2 * NN * 112 * 4, stream);
    hipMemsetAsync(cnt, 0, (size_t)2 * NN * 4, stream);
    hipMemsetAsync(out, 0, 64 * 4, stream);

    dim3 blk(256, 1, 1);
    dim3 gn(NN / 256, 2, 1);   // node kernels, both molecules
    dim3 ge(NE / 256, 2, 1);   // edge kernels, both molecules

    k_transpose<<<dim3(240, 1, 1), blk, 0, stream>>>(c0_w2, w2t0, c1_w2, w2t1);
    k_node_mlp<<<gn, blk, 0, stream>>>(x_r, x_p, h16, ne_w1, ne_b1, ne_w2, ne_b2);
    k_edge_geom<<<ge, blk, 0, stream>>>(ei_r, ei_p, pos_r, pos_p, sh1d, eemb, cnt,
                                        ee_w1, ee_b1, ee_w2, ee_b2);
    k_conv0<<<ge, blk, 0, stream>>>(ei_r, ei_p, eemb, h16, sh1d, c0_b1, c0_w1, w2t0, c0_b2, up0);
    k_up0<<<gn, blk, 0, stream>>>(h16, up0, cnt, h64);
    k_conv1a<<<ge, blk, 0, stream>>>(ei_r, ei_p, eemb, h64, sh1d, c1_b1, c1_w1, w2t1, c1_b2, up1);
    k_conv1b<<<ge, blk, 0, stream>>>(ei_r, ei_p, eemb, h64, sh1d, c1_b1, c1_w1, w2t1, c1_b2, up1);
    k_xf_snode<<<gn, blk, 0, stream>>>(h64, up1, cnt, xf, batch_r, batch_p,
                                       sn_w1, sn_b1, sn_w2, sn_b2, sn_w3, sn_b3, out);
    k_sedge<<<ge, blk, 0, stream>>>(ei_r, ei_p, batch_r, batch_p, sh1d, xf,
                                    se_w1, se_b1, se_w2, se_b2, se_w3, se_b3, out);
}

// Round 3
// 675.149 us; speedup vs baseline: 4.3128x; 3.7825x over previous
//
#include <hip/hip_runtime.h>
#include <math.h>

#define NN 8192
#define NE 65536
#define SQRT3F 1.7320508075688772f
#define INV_SQRT3F 0.5773502691896258f
#define PW 0.17677669529663687f      // 1/sqrt(32) == 0.25/sqrt(2)
#define GSTEP (10.0f/31.0f)
#define GCOEFF (-0.5f/(GSTEP*GSTEP))

typedef _Float16 f16;
typedef f16 f16x8 __attribute__((ext_vector_type(8)));
typedef float f32x4 __attribute__((ext_vector_type(4)));

#define MFMA(acc, a, b) acc = __builtin_amdgcn_mfma_f32_16x16x32_f16(a, b, acc, 0, 0, 0)

// ---------------- prep: build f16 hi/lo split weight arrays, B-operand layout [n][k<=64] ----------------
// rows: k 0..47 = weight, k48 = bias, k49..63 = 0.  row stride 64 f16 = 128B.
__global__ __launch_bounds__(256) void k_prep(const float* __restrict__ c0w1, const float* __restrict__ c0b1,
                                              const float* __restrict__ c1w1, const float* __restrict__ c1b1,
                                              const float* __restrict__ c0w2, const float* __restrict__ c0b2,
                                              const float* __restrict__ c1w2, const float* __restrict__ c1b2,
                                              f16* __restrict__ w1c0hi, f16* __restrict__ w1c0lo,
                                              f16* __restrict__ w1c1hi, f16* __restrict__ w1c1lo,
                                              f16* __restrict__ w2t0hi, f16* __restrict__ w2t0lo,
                                              f16* __restrict__ w2t1hi, f16* __restrict__ w2t1lo) {
    int idx = blockIdx.x * 256 + threadIdx.x;    // grid covers 1280*64 = 81920
    if (idx >= 1280 * 64) return;
    int n = idx >> 6, h = idx & 63;
    {   // c1_w2: 48x1280
        float v = (h < 48) ? c1w2[h * 1280 + n] : (h == 48 ? c1b2[n] : 0.f);
        f16 hi = (f16)v;
        w2t1hi[idx] = hi; w2t1lo[idx] = (f16)(v - (float)hi);
    }
    if (n < 512) {   // c0_w2: 48x512
        float v = (h < 48) ? c0w2[h * 512 + n] : (h == 48 ? c0b2[n] : 0.f);
        f16 hi = (f16)v;
        w2t0hi[idx] = hi; w2t0lo[idx] = (f16)(v - (float)hi);
    }
    if (n < 48) {    // w1: 48x48
        float v0 = (h < 48) ? c0w1[h * 48 + n] : (h == 48 ? c0b1[n] : 0.f);
        f16 h0 = (f16)v0;
        w1c0hi[idx] = h0; w1c0lo[idx] = (f16)(v0 - (float)h0);
        float v1 = (h < 48) ? c1w1[h * 48 + n] : (h == 48 ? c1b1[n] : 0.f);
        f16 h1 = (f16)v1;
        w1c1hi[idx] = h1; w1c1lo[idx] = (f16)(v1 - (float)h1);
    }
}

// ---------------- node MLP: x(32) -> 16 -> 16 (f32 + f16 copy) ----------------
__global__ __launch_bounds__(256) void k_node_mlp(const float* __restrict__ xr, const float* __restrict__ xp,
                                                  float* __restrict__ h16, f16* __restrict__ h16_16,
                                                  const float* __restrict__ w1, const float* __restrict__ b1,
                                                  const float* __restrict__ w2, const float* __restrict__ b2) {
    int mol = blockIdx.y;
    const float* x = mol ? xp : xr;
    float* h = h16 + (size_t)mol * NN * 16;
    f16* h16o = h16_16 + (size_t)mol * NN * 16;
    int v = blockIdx.x * 256 + threadIdx.x;
    float xi[32];
#pragma unroll
    for (int i = 0; i < 32; i++) xi[i] = x[v * 32 + i];
    float a[16];
#pragma unroll
    for (int j = 0; j < 16; j++) a[j] = b1[j];
#pragma unroll
    for (int i = 0; i < 32; i++) {
#pragma unroll
        for (int j = 0; j < 16; j++) a[j] = fmaf(xi[i], w1[i * 16 + j], a[j]);
    }
#pragma unroll
    for (int j = 0; j < 16; j++) a[j] = fmaxf(a[j], 0.f);
    float o[16];
#pragma unroll
    for (int j = 0; j < 16; j++) o[j] = b2[j];
#pragma unroll
    for (int i = 0; i < 16; i++) {
#pragma unroll
        for (int j = 0; j < 16; j++) o[j] = fmaf(a[i], w2[i * 16 + j], o[j]);
    }
#pragma unroll
    for (int j = 0; j < 16; j++) { h[v * 16 + j] = o[j]; h16o[v * 16 + j] = (f16)o[j]; }
}

// ---------------- edge geometry + RBF + edge MLP (32->16->16, f16 out) + dst count ----------------
__global__ __launch_bounds__(256) void k_edge_geom(const int* __restrict__ eir, const int* __restrict__ eip,
                                                   const float* __restrict__ posr, const float* __restrict__ posp,
                                                   float* __restrict__ sh1d, f16* __restrict__ eemb16,
                                                   float* __restrict__ cnt,
                                                   const float* __restrict__ w1, const float* __restrict__ b1,
                                                   const float* __restrict__ w2, const float* __restrict__ b2) {
    int mol = blockIdx.y;
    const int* ei = mol ? eip : eir;
    const float* pos = mol ? posp : posr;
    float* sh_ = sh1d + (size_t)mol * NE * 4;
    f16* em_ = eemb16 + (size_t)mol * NE * 16;
    float* cn_ = cnt + (size_t)mol * NN;
    int e = blockIdx.x * 256 + threadIdx.x;
    int s = ei[e], d = ei[NE + e];
    float ex = pos[d * 3 + 0] - pos[s * 3 + 0];
    float ey = pos[d * 3 + 1] - pos[s * 3 + 1];
    float ez = pos[d * 3 + 2] - pos[s * 3 + 2];
    float dist = sqrtf(ex * ex + ey * ey + ez * ez + 1e-12f);
    float inv = SQRT3F / dist;
    sh_[e * 4 + 0] = ex * inv;
    sh_[e * 4 + 1] = ey * inv;
    sh_[e * 4 + 2] = ez * inv;
    sh_[e * 4 + 3] = dist;
    float g[32];
#pragma unroll
    for (int i = 0; i < 32; i++) {
        float t = dist - (float)i * GSTEP;
        g[i] = __expf(GCOEFF * t * t);
    }
    float a[16];
#pragma unroll
    for (int j = 0; j < 16; j++) a[j] = b1[j];
#pragma unroll
    for (int i = 0; i < 32; i++) {
#pragma unroll
        for (int j = 0; j < 16; j++) a[j] = fmaf(g[i], w1[i * 16 + j], a[j]);
    }
#pragma unroll
    for (int j = 0; j < 16; j++) a[j] = fmaxf(a[j], 0.f);
    float o[16];
#pragma unroll
    for (int j = 0; j < 16; j++) o[j] = b2[j];
#pragma unroll
    for (int i = 0; i < 16; i++) {
#pragma unroll
        for (int j = 0; j < 16; j++) o[j] = fmaf(a[i], w2[i * 16 + j], o[j]);
    }
#pragma unroll
    for (int j = 0; j < 16; j++) em_[e * 16 + j] = (f16)o[j];
    atomicAdd(&cn_[d], 1.0f);
}

// ======================= conv0: MFMA, 64 edges/block =======================
// ea = [eemb16 | h16[d] | h16[s] | 1 | 0pad]; hid = relu(ea @ W1) via MFMA (hi+lo);
// o0/o1 via K-loop over u with A-frag scaled by xu; scatter atomics.
__global__ __launch_bounds__(256) void k_conv0(const int* __restrict__ eir, const int* __restrict__ eip,
                                               const f16* __restrict__ eemb16, const f16* __restrict__ h16_16,
                                               const float* __restrict__ h16f, const float* __restrict__ sh1d,
                                               const f16* __restrict__ w1hi, const f16* __restrict__ w1lo,
                                               const f16* __restrict__ w2hi, const f16* __restrict__ w2lo,
                                               float* __restrict__ up0) {
    __shared__ __align__(16) f16 ea[64 * 72];     // row stride 72 f16 = 144B
    __shared__ __align__(16) f16 hid[64 * 72];
    __shared__ __align__(16) float sc[64 * 20];   // xu[16] per edge, stride 20
    int mol = blockIdx.y;
    const int* ei = mol ? eip : eir;
    const f16* em_ = eemb16 + (size_t)mol * NE * 16;
    const f16* h16_ = h16_16 + (size_t)mol * NN * 16;
    const float* hf_ = h16f + (size_t)mol * NN * 16;
    const float* sh_ = sh1d + (size_t)mol * NE * 4;
    float* up_ = up0 + (size_t)mol * NN * 64;
    int tid = threadIdx.x;
    int e0 = blockIdx.x * 64;
    // ---- phase A: stage ea + pads + scales
    {
        int er = tid >> 2, q = tid & 3;
        int e = e0 + er;
        int s = ei[e], d = ei[NE + e];
        char* earow = (char*)ea + er * 144;
        char* hidrow = (char*)hid + er * 144;
        if (q == 0) {
            const f16x8* src = (const f16x8*)(em_ + (size_t)e * 16);
            ((f16x8*)earow)[0] = src[0]; ((f16x8*)earow)[1] = src[1];
        } else if (q == 1) {
            const f16x8* src = (const f16x8*)(h16_ + (size_t)d * 16);
            ((f16x8*)earow)[2] = src[0]; ((f16x8*)earow)[3] = src[1];
        } else if (q == 2) {
            const f16x8* src = (const f16x8*)(h16_ + (size_t)s * 16);
            ((f16x8*)earow)[4] = src[0]; ((f16x8*)earow)[5] = src[1];
        } else {
            f16x8 z8 = {}; f16x8 o8 = {}; o8[0] = (f16)1.0f;
            ((f16x8*)earow)[6] = o8; ((f16x8*)earow)[7] = z8; ((f16x8*)earow)[8] = z8;
            ((f16x8*)hidrow)[6] = o8; ((f16x8*)hidrow)[7] = z8; ((f16x8*)hidrow)[8] = z8;
        }
        float* sr = &sc[er * 20];
#pragma unroll
        for (int k = 0; k < 4; ++k) {
            int ui = q * 4 + k;
            sr[ui] = hf_[(size_t)s * 16 + ui];
        }
    }
    __syncthreads();
    int wv = tid >> 6, l = tid & 63;
    int arow = wv * 16 + (l & 15);
    int koff = (l >> 4) * 16;                       // byte offset of k-chunk
    int voffB = (l & 15) * 128 + koff;
    // ---- phase B: hid-gen via MFMA (3 n-tiles of 16)
    {
        f16x8 a0 = *(const f16x8*)((const char*)ea + arow * 144 + koff);
        f16x8 a1 = *(const f16x8*)((const char*)ea + arow * 144 + koff + 64);
#pragma unroll
        for (int nt = 0; nt < 3; ++nt) {
            f32x4 acc = {0.f, 0.f, 0.f, 0.f};
            const char* hb = (const char*)w1hi + nt * 2048 + voffB;
            const char* lb = (const char*)w1lo + nt * 2048 + voffB;
            MFMA(acc, a0, *(const f16x8*)(hb));
            MFMA(acc, a1, *(const f16x8*)(hb + 64));
            MFMA(acc, a0, *(const f16x8*)(lb));
            MFMA(acc, a1, *(const f16x8*)(lb + 64));
#pragma unroll
            for (int r = 0; r < 4; ++r) {
                int rr = wv * 16 + (l >> 4) * 4 + r;
                hid[rr * 72 + nt * 16 + (l & 15)] = (f16)fmaxf(acc[r], 0.f);
            }
        }
    }
    // own-wave rows only: no barrier needed (DS in-order within wave)
    f16x8 ha0 = *(const f16x8*)((const char*)hid + arow * 144 + koff);
    f16x8 ha1 = *(const f16x8*)((const char*)hid + arow * 144 + koff + 64);
    // ---- phase C: K-loop over u, mats A (rows 0) and B (rows 256)
    f32x4 accA = {0.f, 0.f, 0.f, 0.f}, accB = {0.f, 0.f, 0.f, 0.f};
    const char* w2hB = (const char*)w2hi + voffB;
    const char* w2lB = (const char*)w2lo + voffB;
    int srow = (wv * 16 + (l & 15)) * 20;
#pragma unroll 1
    for (int u = 0; u < 16; ++u) {
        f16 s = (f16)sc[srow + u];
        f16x8 x0 = ha0 * s, x1v = ha1 * s;
        const char* Hb = w2hB + (size_t)u * 2048;
        const char* Lb = w2lB + (size_t)u * 2048;
        MFMA(accA, x0, *(const f16x8*)(Hb));          MFMA(accA, x1v, *(const f16x8*)(Hb + 64));
        MFMA(accA, x0, *(const f16x8*)(Lb));          MFMA(accA, x1v, *(const f16x8*)(Lb + 64));
        MFMA(accB, x0, *(const f16x8*)(Hb + 32768)); MFMA(accB, x1v, *(const f16x8*)(Hb + 32768 + 64));
        MFMA(accB, x0, *(const f16x8*)(Lb + 32768)); MFMA(accB, x1v, *(const f16x8*)(Lb + 32768 + 64));
    }
    // ---- epilogue: atomics.  C-layout: col=l&15 (=w), row=(l>>4)*4+r (=edge in tile)
    int w = l & 15;
#pragma unroll
    for (int r = 0; r < 4; ++r) {
        int el = wv * 16 + (l >> 4) * 4 + r;
        int e = e0 + el;
        int d = ei[NE + e];
        float sh0 = sh_[e * 4 + 0], sh1v = sh_[e * 4 + 1], sh2v = sh_[e * 4 + 2];
        float* ud = up_ + (size_t)d * 64;
        atomicAdd(&ud[w], 0.25f * accA[r]);
        float t = 0.25f * accB[r];
        atomicAdd(&ud[16 + w * 3 + 0], t * sh0);
        atomicAdd(&ud[16 + w * 3 + 1], t * sh1v);
        atomicAdd(&ud[16 + w * 3 + 2], t * sh2v);
    }
}

// ---------------- h64 = pad(h16) + up0 / max(cnt,1)  (+ f16 copy of first 16) ----------------
__global__ __launch_bounds__(256) void k_up0(const float* __restrict__ h16, const float* __restrict__ up0,
                                             const float* __restrict__ cnt, float* __restrict__ h64,
                                             f16* __restrict__ h64_16) {
    int mol = blockIdx.y;
    const float* h_ = h16 + (size_t)mol * NN * 16;
    const float* u_ = up0 + (size_t)mol * NN * 64;
    const float* c_ = cnt + (size_t)mol * NN;
    float* o_ = h64 + (size_t)mol * NN * 64;
    f16* o16_ = h64_16 + (size_t)mol * NN * 16;
    int v = blockIdx.x * 256 + threadIdx.x;
    float rc = 1.0f / fmaxf(c_[v], 1.0f);
#pragma unroll
    for (int c = 0; c < 64; c++) {
        float base = (c < 16) ? h_[v * 16 + c] : 0.f;
        float val = fmaf(u_[v * 64 + c], rc, base);
        o_[v * 64 + c] = val;
        if (c < 16) o16_[v * 16 + c] = (f16)val;
    }
}

// ======================= conv1: MFMA, all 5 mats, 64 edges/block =======================
__global__ __launch_bounds__(256) void k_conv1(const int* __restrict__ eir, const int* __restrict__ eip,
                                               const f16* __restrict__ eemb16, const f16* __restrict__ h64_16,
                                               const float* __restrict__ h64f, const float* __restrict__ sh1d,
                                               const f16* __restrict__ w1hi, const f16* __restrict__ w1lo,
                                               const f16* __restrict__ w2hi, const f16* __restrict__ w2lo,
                                               float* __restrict__ up1) {
    __shared__ __align__(16) f16 ea[64 * 72];
    __shared__ __align__(16) f16 hid[64 * 72];
    __shared__ __align__(16) float sc[64 * 132];   // 8 scales x 16 u, stride 132
    int mol = blockIdx.y;
    const int* ei = mol ? eip : eir;
    const f16* em_ = eemb16 + (size_t)mol * NE * 16;
    const f16* h16_ = h64_16 + (size_t)mol * NN * 16;
    const float* hf_ = h64f + (size_t)mol * NN * 64;
    const float* sh_ = sh1d + (size_t)mol * NE * 4;
    float* up_ = up1 + (size_t)mol * NN * 112;
    int tid = threadIdx.x;
    int e0 = blockIdx.x * 64;
    // ---- phase A
    {
        int er = tid >> 2, q = tid & 3;
        int e = e0 + er;
        int s = ei[e], d = ei[NE + e];
        char* earow = (char*)ea + er * 144;
        char* hidrow = (char*)hid + er * 144;
        if (q == 0) {
            const f16x8* src = (const f16x8*)(em_ + (size_t)e * 16);
            ((f16x8*)earow)[0] = src[0]; ((f16x8*)earow)[1] = src[1];
        } else if (q == 1) {
            const f16x8* src = (const f16x8*)(h16_ + (size_t)d * 16);
            ((f16x8*)earow)[2] = src[0]; ((f16x8*)earow)[3] = src[1];
        } else if (q == 2) {
            const f16x8* src = (const f16x8*)(h16_ + (size_t)s * 16);
            ((f16x8*)earow)[4] = src[0]; ((f16x8*)earow)[5] = src[1];
        } else {
            f16x8 z8 = {}; f16x8 o8 = {}; o8[0] = (f16)1.0f;
            ((f16x8*)earow)[6] = o8; ((f16x8*)earow)[7] = z8; ((f16x8*)earow)[8] = z8;
            ((f16x8*)hidrow)[6] = o8; ((f16x8*)hidrow)[7] = z8; ((f16x8*)hidrow)[8] = z8;
        }
        float sh0 = sh_[e * 4 + 0], sh1v = sh_[e * 4 + 1], sh2v = sh_[e * 4 + 2];
        float* sr = &sc[er * 132];
#pragma unroll
        for (int k = 0; k < 4; ++k) {
            int ui = q * 4 + k;
            float xu = hf_[(size_t)s * 64 + ui];
            float x10 = hf_[(size_t)s * 64 + 16 + ui * 3 + 0];
            float x11 = hf_[(size_t)s * 64 + 16 + ui * 3 + 1];
            float x12 = hf_[(size_t)s * 64 + 16 + ui * 3 + 2];
            float* wp = &sr[ui * 8];
            wp[0] = xu;
            wp[1] = (x10 * sh0 + x11 * sh1v + x12 * sh2v) * INV_SQRT3F;
            wp[2] = x10; wp[3] = x11; wp[4] = x12;
            wp[5] = x11 * sh2v - x12 * sh1v;
            wp[6] = x12 * sh0 - x10 * sh2v;
            wp[7] = x10 * sh1v - x11 * sh0;
        }
    }
    __syncthreads();
    int wv = tid >> 6, l = tid & 63;
    int arow = wv * 16 + (l & 15);
    int koff = (l >> 4) * 16;
    int voffB = (l & 15) * 128 + koff;
    // ---- phase B: hid-gen
    {
        f16x8 a0 = *(const f16x8*)((const char*)ea + arow * 144 + koff);
        f16x8 a1 = *(const f16x8*)((const char*)ea + arow * 144 + koff + 64);
#pragma unroll
        for (int nt = 0; nt < 3; ++nt) {
            f32x4 acc = {0.f, 0.f, 0.f, 0.f};
            const char* hb = (const char*)w1hi + nt * 2048 + voffB;
            const char* lb = (const char*)w1lo + nt * 2048 + voffB;
            MFMA(acc, a0, *(const f16x8*)(hb));
            MFMA(acc, a1, *(const f16x8*)(hb + 64));
            MFMA(acc, a0, *(const f16x8*)(lb));
            MFMA(acc, a1, *(const f16x8*)(lb + 64));
#pragma unroll
            for (int r = 0; r < 4; ++r) {
                int rr = wv * 16 + (l >> 4) * 4 + r;
                hid[rr * 72 + nt * 16 + (l & 15)] = (f16)fmaxf(acc[r], 0.f);
            }
        }
    }
    f16x8 ha0 = *(const f16x8*)((const char*)hid + arow * 144 + koff);
    f16x8 ha1 = *(const f16x8*)((const char*)hid + arow * 144 + koff + 64);
    // ---- phase C: K-loop over u.  Row offsets (bytes): A=0, B=32768, C=65536, D=98304, E=131072
    f32x4 accA = {0.f,0.f,0.f,0.f}, accB = {0.f,0.f,0.f,0.f};
    f32x4 accC0 = {0.f,0.f,0.f,0.f}, accC1 = {0.f,0.f,0.f,0.f}, accC2 = {0.f,0.f,0.f,0.f};
    f32x4 accE0 = {0.f,0.f,0.f,0.f}, accE1 = {0.f,0.f,0.f,0.f}, accE2 = {0.f,0.f,0.f,0.f};
    const char* w2hB = (const char*)w2hi + voffB;
    const char* w2lB = (const char*)w2lo + voffB;
    int srow = (wv * 16 + (l & 15)) * 132;
#pragma unroll 1
    for (int u = 0; u < 16; ++u) {
        float4 sa4 = *(const float4*)&sc[srow + u * 8];
        float4 sb4 = *(const float4*)&sc[srow + u * 8 + 4];
        const char* Hb = w2hB + (size_t)u * 2048;
        const char* Lb = w2lB + (size_t)u * 2048;
        f16 s; f16x8 x0, x1v;
        // xu -> mats A and B
        s = (f16)sa4.x; x0 = ha0 * s; x1v = ha1 * s;
        MFMA(accA, x0, *(const f16x8*)(Hb));          MFMA(accA, x1v, *(const f16x8*)(Hb + 64));
        MFMA(accA, x0, *(const f16x8*)(Lb));          MFMA(accA, x1v, *(const f16x8*)(Lb + 64));
        MFMA(accB, x0, *(const f16x8*)(Hb + 32768)); MFMA(accB, x1v, *(const f16x8*)(Hb + 32768 + 64));
        MFMA(accB, x0, *(const f16x8*)(Lb + 32768)); MFMA(accB, x1v, *(const f16x8*)(Lb + 32768 + 64));
        // du -> mat D into accA
        s = (f16)sa4.y; x0 = ha0 * s; x1v = ha1 * s;
        MFMA(accA, x0, *(const f16x8*)(Hb + 98304)); MFMA(accA, x1v, *(const f16x8*)(Hb + 98304 + 64));
        MFMA(accA, x0, *(const f16x8*)(Lb + 98304)); MFMA(accA, x1v, *(const f16x8*)(Lb + 98304 + 64));
        // C rows shared by 3 scale-sets
        f16x8 Ch0 = *(const f16x8*)(Hb + 65536), Ch1 = *(const f16x8*)(Hb + 65536 + 64);
        f16x8 Cl0 = *(const f16x8*)(Lb + 65536), Cl1 = *(const f16x8*)(Lb + 65536 + 64);
        s = (f16)sa4.z; x0 = ha0 * s; x1v = ha1 * s;
        MFMA(accC0, x0, Ch0); MFMA(accC0, x1v, Ch1); MFMA(accC0, x0, Cl0); MFMA(accC0, x1v, Cl1);
        s = (f16)sa4.w; x0 = ha0 * s; x1v = ha1 * s;
        MFMA(accC1, x0, Ch0); MFMA(accC1, x1v, Ch1); MFMA(accC1, x0, Cl0); MFMA(accC1, x1v, Cl1);
        s = (f16)sb4.x; x0 = ha0 * s; x1v = ha1 * s;
        MFMA(accC2, x0, Ch0); MFMA(accC2, x1v, Ch1); MFMA(accC2, x0, Cl0); MFMA(accC2, x1v, Cl1);
        // E rows shared by 3 scale-sets
        f16x8 Eh0 = *(const f16x8*)(Hb + 131072), Eh1 = *(const f16x8*)(Hb + 131072 + 64);
        f16x8 El0 = *(const f16x8*)(Lb + 131072), El1 = *(const f16x8*)(Lb + 131072 + 64);
        s = (f16)sb4.y; x0 = ha0 * s; x1v = ha1 * s;
        MFMA(accE0, x0, Eh0); MFMA(accE0, x1v, Eh1); MFMA(accE0, x0, El0); MFMA(accE0, x1v, El1);
        s = (f16)sb4.z; x0 = ha0 * s; x1v = ha1 * s;
        MFMA(accE1, x0, Eh0); MFMA(accE1, x1v, Eh1); MFMA(accE1, x0, El0); MFMA(accE1, x1v, El1);
        s = (f16)sb4.w; x0 = ha0 * s; x1v = ha1 * s;
        MFMA(accE2, x0, Eh0); MFMA(accE2, x1v, Eh1); MFMA(accE2, x0, El0); MFMA(accE2, x1v, El1);
    }
    // ---- epilogue
    int w = l & 15;
#pragma unroll
    for (int r = 0; r < 4; ++r) {
        int el = wv * 16 + (l >> 4) * 4 + r;
        int e = e0 + el;
        int d = ei[NE + e];
        float sh0 = sh_[e * 4 + 0], sh1v = sh_[e * 4 + 1], sh2v = sh_[e * 4 + 2];
        float* ud = up_ + (size_t)d * 112;
        atomicAdd(&ud[w], PW * accA[r]);
        float tb = accB[r];
        atomicAdd(&ud[16 + w * 3 + 0], PW * (tb * sh0 + accC0[r]));
        atomicAdd(&ud[16 + w * 3 + 1], PW * (tb * sh1v + accC1[r]));
        atomicAdd(&ud[16 + w * 3 + 2], PW * (tb * sh2v + accC2[r]));
        atomicAdd(&ud[64 + w * 3 + 0], PW * accE0[r]);
        atomicAdd(&ud[64 + w * 3 + 1], PW * accE1[r]);
        atomicAdd(&ud[64 + w * 3 + 2], PW * accE2[r]);
    }
}

// ---------------- xf = h64[:16] + up1[:16]/cnt; s_nodes MLP; bucket into out ----------------
__global__ __launch_bounds__(256) void k_xf_snode(const float* __restrict__ h64, const float* __restrict__ up1,
                                                  const float* __restrict__ cnt, float* __restrict__ xf,
                                                  const int* __restrict__ batchr, const int* __restrict__ batchp,
                                                  const float* __restrict__ w1, const float* __restrict__ b1,
                                                  const float* __restrict__ w2, const float* __restrict__ b2,
                                                  const float* __restrict__ w3, const float* __restrict__ b3,
                                                  float* __restrict__ out) {
    __shared__ float buck[64];
    int tid = threadIdx.x;
    if (tid < 64) buck[tid] = 0.f;
    __syncthreads();
    int mol = blockIdx.y;
    float sign = mol ? 1.f : -1.f;
    const int* batch = mol ? batchp : batchr;
    const float* h_ = h64 + (size_t)mol * NN * 64;
    const float* u_ = up1 + (size_t)mol * NN * 112;
    const float* c_ = cnt + (size_t)mol * NN;
    float* xf_ = xf + (size_t)mol * NN * 16;
    int v = blockIdx.x * 256 + tid;
    float rc = 1.0f / fmaxf(c_[v], 1.0f);
    float xv[16];
#pragma unroll
    for (int c = 0; c < 16; c++) {
        xv[c] = fmaf(u_[v * 112 + c], rc, h_[v * 64 + c]);
        xf_[v * 16 + c] = xv[c];
    }
    float a[32];
#pragma unroll
    for (int j = 0; j < 32; j++) a[j] = b1[j];
#pragma unroll
    for (int i = 0; i < 16; i++) {
#pragma unroll
        for (int j = 0; j < 32; j++) a[j] = fmaf(xv[i], w1[i * 32 + j], a[j]);
    }
#pragma unroll
    for (int j = 0; j < 32; j++) a[j] = fmaxf(a[j], 0.f);
    float bb[16];
#pragma unroll
    for (int j = 0; j < 16; j++) bb[j] = b2[j];
#pragma unroll
    for (int i = 0; i < 32; i++) {
#pragma unroll
        for (int j = 0; j < 16; j++) bb[j] = fmaf(a[i], w2[i * 16 + j], bb[j]);
    }
#pragma unroll
    for (int j = 0; j < 16; j++) bb[j] = fmaxf(bb[j], 0.f);
    float val = b3[0];
#pragma unroll
    for (int i = 0; i < 16; i++) val = fmaf(bb[i], w3[i], val);
    atomicAdd(&buck[batch[v]], val);
    __syncthreads();
    if (tid < 64) atomicAdd(&out[tid], sign * buck[tid]);
}

// ---------------- s_edges MLP (64->16->16->1), bucket by batch[src] into out ----------------
__global__ __launch_bounds__(256) void k_sedge(const int* __restrict__ eir, const int* __restrict__ eip,
                                               const int* __restrict__ batchr, const int* __restrict__ batchp,
                                               const float* __restrict__ sh1d, const float* __restrict__ xf,
                                               const float* __restrict__ w1, const float* __restrict__ b1,
                                               const float* __restrict__ w2, const float* __restrict__ b2,
                                               const float* __restrict__ w3, const float* __restrict__ b3,
                                               float* __restrict__ out) {
    __shared__ float buck[64];
    int tid = threadIdx.x;
    if (tid < 64) buck[tid] = 0.f;
    __syncthreads();
    int mol = blockIdx.y;
    float sign = mol ? 1.f : -1.f;
    const int* ei = mol ? eip : eir;
    const int* batch = mol ? batchp : batchr;
    const float* sh_ = sh1d + (size_t)mol * NE * 4;
    const float* xf_ = xf + (size_t)mol * NN * 16;
    int e = blockIdx.x * 256 + tid;
    int s = ei[e], d = ei[NE + e];
    float dist = sh_[e * 4 + 3];
    float in[64];
#pragma unroll
    for (int i = 0; i < 32; i++) {
        float t = dist - (float)i * GSTEP;
        in[i] = __expf(GCOEFF * t * t);
    }
#pragma unroll
    for (int i = 0; i < 16; i++) in[32 + i] = xf_[s * 16 + i];
#pragma unroll
    for (int i = 0; i < 16; i++) in[48 + i] = xf_[d * 16 + i];
    float a[16];
#pragma unroll
    for (int j = 0; j < 16; j++) a[j] = b1[j];
#pragma unroll
    for (int i = 0; i < 64; i++) {
#pragma unroll
        for (int j = 0; j < 16; j++) a[j] = fmaf(in[i], w1[i * 16 + j], a[j]);
    }
#pragma unroll
    for (int j = 0; j < 16; j++) a[j] = fmaxf(a[j], 0.f);
    float bb[16];
#pragma unroll
    for (int j = 0; j < 16; j++) bb[j] = b2[j];
#pragma unroll
    for (int i = 0; i < 16; i++) {
#pragma unroll
        for (int j = 0; j < 16; j++) bb[j] = fmaf(a[i], w2[i * 16 + j], bb[j]);
    }
#pragma unroll
    for (int j = 0; j < 16; j++) bb[j] = fmaxf(bb[j], 0.f);
    float val = b3[0];
#pragma unroll
    for (int i = 0; i < 16; i++) val = fmaf(bb[i], w3[i], val);
    atomicAdd(&buck[batch[s]], val);
    __syncthreads();
    if (tid < 64) atomicAdd(&out[tid], sign * buck[tid]);
}

extern "C" void kernel_launch(void* const* d_in, const int* in_sizes, int n_in,
                              void* d_out, int out_size, void* d_ws, size_t ws_size,
                              hipStream_t stream) {
    const float* x_r = (const float*)d_in[0];
    const float* pos_r = (const float*)d_in[1];
    const int* ei_r = (const int*)d_in[2];
    const int* batch_r = (const int*)d_in[3];
    const float* x_p = (const float*)d_in[4];
    const float* pos_p = (const float*)d_in[5];
    const int* ei_p = (const int*)d_in[6];
    const int* batch_p = (const int*)d_in[7];
    const float* ne_w1 = (const float*)d_in[8];
    const float* ne_b1 = (const float*)d_in[9];
    const float* ne_w2 = (const float*)d_in[10];
    const float* ne_b2 = (const float*)d_in[11];
    const float* ee_w1 = (const float*)d_in[12];
    const float* ee_b1 = (const float*)d_in[13];
    const float* ee_w2 = (const float*)d_in[14];
    const float* ee_b2 = (const float*)d_in[15];
    const float* c0_w1 = (const float*)d_in[16];
    const float* c0_b1 = (const float*)d_in[17];
    const float* c0_w2 = (const float*)d_in[18];
    const float* c0_b2 = (const float*)d_in[19];
    const float* c1_w1 = (const float*)d_in[20];
    const float* c1_b1 = (const float*)d_in[21];
    const float* c1_w2 = (const float*)d_in[22];
    const float* c1_b2 = (const float*)d_in[23];
    const float* sn_w1 = (const float*)d_in[24];
    const float* sn_b1 = (const float*)d_in[25];
    const float* sn_w2 = (const float*)d_in[26];
    const float* sn_b2 = (const float*)d_in[27];
    const float* sn_w3 = (const float*)d_in[28];
    const float* sn_b3 = (const float*)d_in[29];
    const float* se_w1 = (const float*)d_in[30];
    const float* se_b1 = (const float*)d_in[31];
    const float* se_w2 = (const float*)d_in[32];
    const float* se_b2 = (const float*)d_in[33];
    const float* se_w3 = (const float*)d_in[34];
    const float* se_b3 = (const float*)d_in[35];
    float* out = (float*)d_out;

    char* p = (char*)d_ws;
    auto alloc = [&](size_t bytes) { char* r = p; p += (bytes + 255) & ~(size_t)255; return r; };
    f16* w2t1hi = (f16*)alloc(1280 * 64 * 2);
    f16* w2t1lo = (f16*)alloc(1280 * 64 * 2);
    f16* w2t0hi = (f16*)alloc(512 * 64 * 2);
    f16* w2t0lo = (f16*)alloc(512 * 64 * 2);
    f16* w1c0hi = (f16*)alloc(48 * 64 * 2);
    f16* w1c0lo = (f16*)alloc(48 * 64 * 2);
    f16* w1c1hi = (f16*)alloc(48 * 64 * 2);
    f16* w1c1lo = (f16*)alloc(48 * 64 * 2);
    f16* eemb16 = (f16*)alloc((size_t)2 * NE * 16 * 2);
    f16* h16_16 = (f16*)alloc((size_t)2 * NN * 16 * 2);
    f16* h64_16 = (f16*)alloc((size_t)2 * NN * 16 * 2);
    float* h16f = (float*)alloc((size_t)2 * NN * 16 * 4);
    float* sh1d = (float*)alloc((size_t)2 * NE * 4 * 4);
    float* cnt  = (float*)alloc((size_t)2 * NN * 4);
    float* up0  = (float*)alloc((size_t)2 * NN * 64 * 4);
    float* h64f = (float*)alloc((size_t)2 * NN * 64 * 4);
    float* up1  = (float*)alloc((size_t)2 * NN * 112 * 4);
    float* xf   = (float*)alloc((size_t)2 * NN * 16 * 4);
    (void)ws_size; (void)n_in; (void)in_sizes; (void)out_size;

    hipMemsetAsync(up0, 0, (size_t)2 * NN * 64 * 4, stream);
    hipMemsetAsync(up1, 0, (size_t)2 * NN * 112 * 4, stream);
    hipMemsetAsync(cnt, 0, (size_t)2 * NN * 4, stream);
    hipMemsetAsync(out, 0, 64 * 4, stream);

    dim3 blk(256, 1, 1);
    dim3 gn(NN / 256, 2, 1);
    dim3 ge(NE / 256, 2, 1);
    dim3 gc(NE / 64, 2, 1);

    k_prep<<<dim3(320, 1, 1), blk, 0, stream>>>(c0_w1, c0_b1, c1_w1, c1_b1, c0_w2, c0_b2, c1_w2, c1_b2,
                                                w1c0hi, w1c0lo, w1c1hi, w1c1lo,
                                                w2t0hi, w2t0lo, w2t1hi, w2t1lo);
    k_node_mlp<<<gn, blk, 0, stream>>>(x_r, x_p, h16f, h16_16, ne_w1, ne_b1, ne_w2, ne_b2);
    k_edge_geom<<<ge, blk, 0, stream>>>(ei_r, ei_p, pos_r, pos_p, sh1d, eemb16, cnt,
                                        ee_w1, ee_b1, ee_w2, ee_b2);
    k_conv0<<<gc, blk, 0, stream>>>(ei_r, ei_p, eemb16, h16_16, h16f, sh1d,
                                    w1c0hi, w1c0lo, w2t0hi, w2t0lo, up0);
    k_up0<<<gn, blk, 0, stream>>>(h16f, up0, cnt, h64f, h64_16);
    k_conv1<<<gc, blk, 0, stream>>>(ei_r, ei_p, eemb16, h64_16, h64f, sh1d,
                                    w1c1hi, w1c1lo, w2t1hi, w2t1lo, up1);
    k_xf_snode<<<gn, blk, 0, stream>>>(h64f, up1, cnt, xf, batch_r, batch_p,
                                       sn_w1, sn_b1, sn_w2, sn_b2, sn_w3, sn_b3, out);
    k_sedge<<<ge, blk, 0, stream>>>(ei_r, ei_p, batch_r, batch_p, sh1d, xf,
                                    se_w1, se_b1, se_w2, se_b2, se_w3, se_b3, out);
}

// Round 4
// 387.825 us; speedup vs baseline: 7.5081x; 1.7409x over previous
//
#include <hip/hip_runtime.h>
#include <math.h>

#define NN 8192
#define NE 65536
#define SQRT3F 1.7320508075688772f
#define INV_SQRT3F 0.5773502691896258f
#define PW 0.17677669529663687f      // 1/sqrt(32) == 0.25/sqrt(2)
#define GSTEP (10.0f/31.0f)
#define GCOEFF (-0.5f/(GSTEP*GSTEP))

typedef _Float16 f16;
typedef f16 f16x8 __attribute__((ext_vector_type(8)));
typedef float f32x4 __attribute__((ext_vector_type(4)));

#define MFMA(acc, a, b) acc = __builtin_amdgcn_mfma_f32_16x16x32_f16(a, b, acc, 0, 0, 0)

// ---------------- prep: f16 weights, B-operand layout [n][k=64] (k48 = bias, rest 0) ----------------
__global__ __launch_bounds__(256) void k_prep(const float* __restrict__ c0w1, const float* __restrict__ c0b1,
                                              const float* __restrict__ c1w1, const float* __restrict__ c1b1,
                                              const float* __restrict__ c0w2, const float* __restrict__ c0b2,
                                              const float* __restrict__ c1w2, const float* __restrict__ c1b2,
                                              f16* __restrict__ w1c0, f16* __restrict__ w1c1,
                                              f16* __restrict__ w2t0, f16* __restrict__ w2t1) {
    int idx = blockIdx.x * 256 + threadIdx.x;    // grid covers 1280*64 = 81920
    if (idx >= 1280 * 64) return;
    int n = idx >> 6, h = idx & 63;
    w2t1[idx] = (f16)((h < 48) ? c1w2[h * 1280 + n] : (h == 48 ? c1b2[n] : 0.f));
    if (n < 512) w2t0[idx] = (f16)((h < 48) ? c0w2[h * 512 + n] : (h == 48 ? c0b2[n] : 0.f));
    if (n < 48) {
        w1c0[idx] = (f16)((h < 48) ? c0w1[h * 48 + n] : (h == 48 ? c0b1[n] : 0.f));
        w1c1[idx] = (f16)((h < 48) ? c1w1[h * 48 + n] : (h == 48 ? c1b1[n] : 0.f));
    }
}

// ---------------- node MLP: x(32) -> 16 -> 16 (f32 + f16 copy) ----------------
__global__ __launch_bounds__(256) void k_node_mlp(const float* __restrict__ xr, const float* __restrict__ xp,
                                                  float* __restrict__ h16, f16* __restrict__ h16_16,
                                                  const float* __restrict__ w1, const float* __restrict__ b1,
                                                  const float* __restrict__ w2, const float* __restrict__ b2) {
    int mol = blockIdx.y;
    const float* x = mol ? xp : xr;
    float* h = h16 + (size_t)mol * NN * 16;
    f16* h16o = h16_16 + (size_t)mol * NN * 16;
    int v = blockIdx.x * 256 + threadIdx.x;
    float xi[32];
#pragma unroll
    for (int i = 0; i < 32; i++) xi[i] = x[v * 32 + i];
    float a[16];
#pragma unroll
    for (int j = 0; j < 16; j++) a[j] = b1[j];
#pragma unroll
    for (int i = 0; i < 32; i++) {
#pragma unroll
        for (int j = 0; j < 16; j++) a[j] = fmaf(xi[i], w1[i * 16 + j], a[j]);
    }
#pragma unroll
    for (int j = 0; j < 16; j++) a[j] = fmaxf(a[j], 0.f);
    float o[16];
#pragma unroll
    for (int j = 0; j < 16; j++) o[j] = b2[j];
#pragma unroll
    for (int i = 0; i < 16; i++) {
#pragma unroll
        for (int j = 0; j < 16; j++) o[j] = fmaf(a[i], w2[i * 16 + j], o[j]);
    }
#pragma unroll
    for (int j = 0; j < 16; j++) { h[v * 16 + j] = o[j]; h16o[v * 16 + j] = (f16)o[j]; }
}

// ---------------- edge geometry + RBF + edge MLP (32->16->16, f16 out) + dst count ----------------
__global__ __launch_bounds__(256) void k_edge_geom(const int* __restrict__ eir, const int* __restrict__ eip,
                                                   const float* __restrict__ posr, const float* __restrict__ posp,
                                                   float* __restrict__ sh1d, f16* __restrict__ eemb16,
                                                   float* __restrict__ cnt,
                                                   const float* __restrict__ w1, const float* __restrict__ b1,
                                                   const float* __restrict__ w2, const float* __restrict__ b2) {
    int mol = blockIdx.y;
    const int* ei = mol ? eip : eir;
    const float* pos = mol ? posp : posr;
    float* sh_ = sh1d + (size_t)mol * NE * 4;
    f16* em_ = eemb16 + (size_t)mol * NE * 16;
    float* cn_ = cnt + (size_t)mol * NN;
    int e = blockIdx.x * 256 + threadIdx.x;
    int s = ei[e], d = ei[NE + e];
    float ex = pos[d * 3 + 0] - pos[s * 3 + 0];
    float ey = pos[d * 3 + 1] - pos[s * 3 + 1];
    float ez = pos[d * 3 + 2] - pos[s * 3 + 2];
    float dist = sqrtf(ex * ex + ey * ey + ez * ez + 1e-12f);
    float inv = SQRT3F / dist;
    sh_[e * 4 + 0] = ex * inv;
    sh_[e * 4 + 1] = ey * inv;
    sh_[e * 4 + 2] = ez * inv;
    sh_[e * 4 + 3] = dist;
    float g[32];
#pragma unroll
    for (int i = 0; i < 32; i++) {
        float t = dist - (float)i * GSTEP;
        g[i] = __expf(GCOEFF * t * t);
    }
    float a[16];
#pragma unroll
    for (int j = 0; j < 16; j++) a[j] = b1[j];
#pragma unroll
    for (int i = 0; i < 32; i++) {
#pragma unroll
        for (int j = 0; j < 16; j++) a[j] = fmaf(g[i], w1[i * 16 + j], a[j]);
    }
#pragma unroll
    for (int j = 0; j < 16; j++) a[j] = fmaxf(a[j], 0.f);
    float o[16];
#pragma unroll
    for (int j = 0; j < 16; j++) o[j] = b2[j];
#pragma unroll
    for (int i = 0; i < 16; i++) {
#pragma unroll
        for (int j = 0; j < 16; j++) o[j] = fmaf(a[i], w2[i * 16 + j], o[j]);
    }
#pragma unroll
    for (int j = 0; j < 16; j++) em_[e * 16 + j] = (f16)o[j];
    atomicAdd(&cn_[d], 1.0f);
}

// ======================= conv0: MFMA, 128 edges/block, 32/wave, no barriers =======================
__global__ __launch_bounds__(256) void k_conv0(const int* __restrict__ eir, const int* __restrict__ eip,
                                               const f16* __restrict__ eemb16, const f16* __restrict__ h16_16,
                                               const float* __restrict__ h16f, const float* __restrict__ sh1d,
                                               const f16* __restrict__ w1h, const f16* __restrict__ w2h,
                                               float* __restrict__ up0) {
    __shared__ __align__(16) f16 ea[128 * 72];    // 144B/row; reused as hid (k48=1 pad shared)
    __shared__ __align__(16) f16 sc0[128 * 24];   // 48B/row: 16 xu scales + pad
    int mol = blockIdx.y;
    const int* ei = mol ? eip : eir;
    const f16* em_ = eemb16 + (size_t)mol * NE * 16;
    const f16* h16_ = h16_16 + (size_t)mol * NN * 16;
    const float* hf_ = h16f + (size_t)mol * NN * 16;
    const float* sh_ = sh1d + (size_t)mol * NE * 4;
    float* up_ = up0 + (size_t)mol * NN * 64;
    int tid = threadIdx.x;
    int e0 = blockIdx.x * 128;
    // ---- phase A: each wave stages its own 32 edges (2 threads/edge)
    {
        int er = tid >> 1, half = tid & 1;
        int e = e0 + er;
        int s = ei[e], d = ei[NE + e];
        char* row = (char*)ea + er * 144;
        if (half == 0) {
            const f16x8* p = (const f16x8*)(em_ + (size_t)e * 16);
            ((f16x8*)row)[0] = p[0]; ((f16x8*)row)[1] = p[1];
            const f16x8* q = (const f16x8*)(h16_ + (size_t)d * 16);
            ((f16x8*)row)[2] = q[0]; ((f16x8*)row)[3] = q[1];
        } else {
            const f16x8* q = (const f16x8*)(h16_ + (size_t)s * 16);
            ((f16x8*)row)[4] = q[0]; ((f16x8*)row)[5] = q[1];
            f16x8 z = {}; f16x8 o = {}; o[0] = (f16)1.0f;
            ((f16x8*)row)[6] = o; ((f16x8*)row)[7] = z; ((f16x8*)row)[8] = z;
        }
        int u0 = half * 8;
        float4 xa = *(const float4*)(hf_ + (size_t)s * 16 + u0);
        float4 xb = *(const float4*)(hf_ + (size_t)s * 16 + u0 + 4);
        f16x8 sv;
        sv[0] = (f16)xa.x; sv[1] = (f16)xa.y; sv[2] = (f16)xa.z; sv[3] = (f16)xa.w;
        sv[4] = (f16)xb.x; sv[5] = (f16)xb.y; sv[6] = (f16)xb.z; sv[7] = (f16)xb.w;
        *(f16x8*)((char*)sc0 + er * 48 + half * 16) = sv;
    }
    int wv = tid >> 6, l = tid & 63;
    int koff = (l >> 4) * 16;
    int voffB = (l & 15) * 128 + koff;
    int rbase = wv * 32;
    // ---- phase B: hid-gen (per wave, in-wave LDS ordering)
#pragma unroll
    for (int t = 0; t < 2; t++) {
        int arow = rbase + t * 16 + (l & 15);
        f16x8 a0 = *(const f16x8*)((const char*)ea + arow * 144 + koff);
        f16x8 a1 = *(const f16x8*)((const char*)ea + arow * 144 + koff + 64);
        f32x4 hacc[3];
#pragma unroll
        for (int nt = 0; nt < 3; nt++) {
            hacc[nt] = (f32x4){0.f, 0.f, 0.f, 0.f};
            const char* hb = (const char*)w1h + nt * 2048 + voffB;
            MFMA(hacc[nt], a0, *(const f16x8*)(hb));
            MFMA(hacc[nt], a1, *(const f16x8*)(hb + 64));
        }
#pragma unroll
        for (int nt = 0; nt < 3; nt++)
#pragma unroll
            for (int r = 0; r < 4; r++) {
                int rr = rbase + t * 16 + (l >> 4) * 4 + r;
                ea[rr * 72 + nt * 16 + (l & 15)] = (f16)fmaxf(hacc[nt][r], 0.f);
            }
    }
    f16x8 ha0[2], ha1[2];
#pragma unroll
    for (int t = 0; t < 2; t++) {
        int arow = rbase + t * 16 + (l & 15);
        ha0[t] = *(const f16x8*)((const char*)ea + arow * 144 + koff);
        ha1[t] = *(const f16x8*)((const char*)ea + arow * 144 + koff + 64);
    }
    // ---- phase C: K-loop over u, mats A(0), B(+32768 bytes)
    f32x4 accA[2] = {}, accB[2] = {};
    const char* wB = (const char*)w2h + voffB;
#pragma unroll 1
    for (int u = 0; u < 16; ++u) {
        const char* Hb = wB + (size_t)u * 2048;
        f16x8 A0 = *(const f16x8*)(Hb);
        f16x8 A1 = *(const f16x8*)(Hb + 64);
        f16x8 B0 = *(const f16x8*)(Hb + 32768);
        f16x8 B1 = *(const f16x8*)(Hb + 32768 + 64);
#pragma unroll
        for (int t = 0; t < 2; t++) {
            f16 s = *(const f16*)((const char*)sc0 + (rbase + t * 16 + (l & 15)) * 48 + u * 2);
            f16x8 x0 = ha0[t] * s, x1 = ha1[t] * s;
            MFMA(accA[t], x0, A0); MFMA(accA[t], x1, A1);
            MFMA(accB[t], x0, B0); MFMA(accB[t], x1, B1);
        }
    }
    // ---- epilogue
    int w = l & 15;
#pragma unroll
    for (int t = 0; t < 2; t++)
#pragma unroll
        for (int r = 0; r < 4; r++) {
            int e = e0 + rbase + t * 16 + (l >> 4) * 4 + r;
            int d = ei[NE + e];
            float4 shv = *(const float4*)(sh_ + (size_t)e * 4);
            float* ud = up_ + (size_t)d * 64;
            atomicAdd(&ud[w], 0.25f * accA[t][r]);
            float tb = 0.25f * accB[t][r];
            atomicAdd(&ud[16 + w * 3 + 0], tb * shv.x);
            atomicAdd(&ud[16 + w * 3 + 1], tb * shv.y);
            atomicAdd(&ud[16 + w * 3 + 2], tb * shv.z);
        }
}

// ---------------- h64 = pad(h16) + up0 / max(cnt,1)  (+ f16 copy of first 16) ----------------
__global__ __launch_bounds__(256) void k_up0(const float* __restrict__ h16, const float* __restrict__ up0,
                                             const float* __restrict__ cnt, float* __restrict__ h64,
                                             f16* __restrict__ h64_16) {
    int mol = blockIdx.y;
    const float* h_ = h16 + (size_t)mol * NN * 16;
    const float* u_ = up0 + (size_t)mol * NN * 64;
    const float* c_ = cnt + (size_t)mol * NN;
    float* o_ = h64 + (size_t)mol * NN * 64;
    f16* o16_ = h64_16 + (size_t)mol * NN * 16;
    int v = blockIdx.x * 256 + threadIdx.x;
    float rc = 1.0f / fmaxf(c_[v], 1.0f);
#pragma unroll
    for (int c = 0; c < 64; c++) {
        float base = (c < 16) ? h_[v * 16 + c] : 0.f;
        float val = fmaf(u_[v * 64 + c], rc, base);
        o_[v * 64 + c] = val;
        if (c < 16) o16_[v * 16 + c] = (f16)val;
    }
}

// ======================= conv1: MFMA, all 5 mats, 128 edges/block, 32/wave =======================
__global__ __launch_bounds__(256) void k_conv1(const int* __restrict__ eir, const int* __restrict__ eip,
                                               const f16* __restrict__ eemb16, const f16* __restrict__ h64_16,
                                               const float* __restrict__ h64f, const float* __restrict__ sh1d,
                                               const f16* __restrict__ w1h, const f16* __restrict__ w2h,
                                               float* __restrict__ up1) {
    __shared__ __align__(16) f16 ea[128 * 72];     // 18.4KB, reused as hid
    __shared__ __align__(16) f16 sc[128 * 136];    // 272B/row: 16u x 8 f16 scales + 16B pad
    int mol = blockIdx.y;
    const int* ei = mol ? eip : eir;
    const f16* em_ = eemb16 + (size_t)mol * NE * 16;
    const f16* h16_ = h64_16 + (size_t)mol * NN * 16;
    const float* hf_ = h64f + (size_t)mol * NN * 64;
    const float* sh_ = sh1d + (size_t)mol * NE * 4;
    float* up_ = up1 + (size_t)mol * NN * 112;
    int tid = threadIdx.x;
    int e0 = blockIdx.x * 128;
    // ---- phase A: stage ea + scales (2 threads/edge, wave-private rows)
    {
        int er = tid >> 1, half = tid & 1;
        int e = e0 + er;
        int s = ei[e], d = ei[NE + e];
        char* row = (char*)ea + er * 144;
        if (half == 0) {
            const f16x8* p = (const f16x8*)(em_ + (size_t)e * 16);
            ((f16x8*)row)[0] = p[0]; ((f16x8*)row)[1] = p[1];
            const f16x8* q = (const f16x8*)(h16_ + (size_t)d * 16);
            ((f16x8*)row)[2] = q[0]; ((f16x8*)row)[3] = q[1];
        } else {
            const f16x8* q = (const f16x8*)(h16_ + (size_t)s * 16);
            ((f16x8*)row)[4] = q[0]; ((f16x8*)row)[5] = q[1];
            f16x8 z = {}; f16x8 o = {}; o[0] = (f16)1.0f;
            ((f16x8*)row)[6] = o; ((f16x8*)row)[7] = z; ((f16x8*)row)[8] = z;
        }
        float4 shv = *(const float4*)(sh_ + (size_t)e * 4);
        const float* hfs = hf_ + (size_t)s * 64;
        int u0 = half * 8;
        float4 xa = *(const float4*)(hfs + u0);
        float4 xb = *(const float4*)(hfs + u0 + 4);
        float xuv[8] = {xa.x, xa.y, xa.z, xa.w, xb.x, xb.y, xb.z, xb.w};
        float x1[24];
#pragma unroll
        for (int q2 = 0; q2 < 6; q2++) {
            float4 v = *(const float4*)(hfs + 16 + u0 * 3 + q2 * 4);
            x1[q2 * 4 + 0] = v.x; x1[q2 * 4 + 1] = v.y; x1[q2 * 4 + 2] = v.z; x1[q2 * 4 + 3] = v.w;
        }
#pragma unroll
        for (int k = 0; k < 8; k++) {
            float x10 = x1[k * 3], x11 = x1[k * 3 + 1], x12 = x1[k * 3 + 2];
            f16x8 sv;
            sv[0] = (f16)xuv[k];
            sv[1] = (f16)((x10 * shv.x + x11 * shv.y + x12 * shv.z) * INV_SQRT3F);
            sv[2] = (f16)x10; sv[3] = (f16)x11; sv[4] = (f16)x12;
            sv[5] = (f16)(x11 * shv.z - x12 * shv.y);
            sv[6] = (f16)(x12 * shv.x - x10 * shv.z);
            sv[7] = (f16)(x10 * shv.y - x11 * shv.x);
            *(f16x8*)((char*)sc + er * 272 + (u0 + k) * 16) = sv;
        }
    }
    int wv = tid >> 6, l = tid & 63;
    int koff = (l >> 4) * 16;
    int voffB = (l & 15) * 128 + koff;
    int rbase = wv * 32;
    // ---- phase B: hid-gen
#pragma unroll
    for (int t = 0; t < 2; t++) {
        int arow = rbase + t * 16 + (l & 15);
        f16x8 a0 = *(const f16x8*)((const char*)ea + arow * 144 + koff);
        f16x8 a1 = *(const f16x8*)((const char*)ea + arow * 144 + koff + 64);
        f32x4 hacc[3];
#pragma unroll
        for (int nt = 0; nt < 3; nt++) {
            hacc[nt] = (f32x4){0.f, 0.f, 0.f, 0.f};
            const char* hb = (const char*)w1h + nt * 2048 + voffB;
            MFMA(hacc[nt], a0, *(const f16x8*)(hb));
            MFMA(hacc[nt], a1, *(const f16x8*)(hb + 64));
        }
#pragma unroll
        for (int nt = 0; nt < 3; nt++)
#pragma unroll
            for (int r = 0; r < 4; r++) {
                int rr = rbase + t * 16 + (l >> 4) * 4 + r;
                ea[rr * 72 + nt * 16 + (l & 15)] = (f16)fmaxf(hacc[nt][r], 0.f);
            }
    }
    f16x8 ha0[2], ha1[2];
#pragma unroll
    for (int t = 0; t < 2; t++) {
        int arow = rbase + t * 16 + (l & 15);
        ha0[t] = *(const f16x8*)((const char*)ea + arow * 144 + koff);
        ha1[t] = *(const f16x8*)((const char*)ea + arow * 144 + koff + 64);
    }
    // ---- phase C: K-loop over u. Mat byte offsets: A=0 B=32768 C=65536 D=98304 E=131072
    f32x4 accA[2] = {}, accB[2] = {};
    f32x4 accC[3][2] = {}, accE[3][2] = {};
    const char* wB = (const char*)w2h + voffB;
#pragma unroll 1
    for (int u = 0; u < 16; ++u) {
        const char* Hb = wB + (size_t)u * 2048;
        f16x8 A0 = *(const f16x8*)(Hb);
        f16x8 A1 = *(const f16x8*)(Hb + 64);
        f16x8 B0 = *(const f16x8*)(Hb + 32768), B1 = *(const f16x8*)(Hb + 32768 + 64);
        f16x8 C0 = *(const f16x8*)(Hb + 65536), C1 = *(const f16x8*)(Hb + 65536 + 64);
        f16x8 D0 = *(const f16x8*)(Hb + 98304), D1 = *(const f16x8*)(Hb + 98304 + 64);
        f16x8 E0 = *(const f16x8*)(Hb + 131072), E1 = *(const f16x8*)(Hb + 131072 + 64);
#pragma unroll
        for (int t = 0; t < 2; t++) {
            f16x8 sv = *(const f16x8*)((const char*)sc + (rbase + t * 16 + (l & 15)) * 272 + u * 16);
            f16 s; f16x8 x0, x1;
            s = sv[0]; x0 = ha0[t] * s; x1 = ha1[t] * s;
            MFMA(accA[t], x0, A0); MFMA(accA[t], x1, A1);
            MFMA(accB[t], x0, B0); MFMA(accB[t], x1, B1);
            s = sv[1]; x0 = ha0[t] * s; x1 = ha1[t] * s;
            MFMA(accA[t], x0, D0); MFMA(accA[t], x1, D1);
#pragma unroll
            for (int c = 0; c < 3; c++) {
                s = sv[2 + c]; x0 = ha0[t] * s; x1 = ha1[t] * s;
                MFMA(accC[c][t], x0, C0); MFMA(accC[c][t], x1, C1);
            }
#pragma unroll
            for (int c = 0; c < 3; c++) {
                s = sv[5 + c]; x0 = ha0[t] * s; x1 = ha1[t] * s;
                MFMA(accE[c][t], x0, E0); MFMA(accE[c][t], x1, E1);
            }
        }
    }
    // ---- epilogue
    int w = l & 15;
#pragma unroll
    for (int t = 0; t < 2; t++)
#pragma unroll
        for (int r = 0; r < 4; r++) {
            int e = e0 + rbase + t * 16 + (l >> 4) * 4 + r;
            int d = ei[NE + e];
            float4 shv = *(const float4*)(sh_ + (size_t)e * 4);
            float* ud = up_ + (size_t)d * 112;
            atomicAdd(&ud[w], PW * accA[t][r]);
            atomicAdd(&ud[16 + w * 3 + 0], PW * (accB[t][r] * shv.x + accC[0][t][r]));
            atomicAdd(&ud[16 + w * 3 + 1], PW * (accB[t][r] * shv.y + accC[1][t][r]));
            atomicAdd(&ud[16 + w * 3 + 2], PW * (accB[t][r] * shv.z + accC[2][t][r]));
            atomicAdd(&ud[64 + w * 3 + 0], PW * accE[0][t][r]);
            atomicAdd(&ud[64 + w * 3 + 1], PW * accE[1][t][r]);
            atomicAdd(&ud[64 + w * 3 + 2], PW * accE[2][t][r]);
        }
}

// ---------------- xf = h64[:16] + up1[:16]/cnt; s_nodes MLP; bucket into out ----------------
__global__ __launch_bounds__(256) void k_xf_snode(const float* __restrict__ h64, const float* __restrict__ up1,
                                                  const float* __restrict__ cnt, float* __restrict__ xf,
                                                  const int* __restrict__ batchr, const int* __restrict__ batchp,
                                                  const float* __restrict__ w1, const float* __restrict__ b1,
                                                  const float* __restrict__ w2, const float* __restrict__ b2,
                                                  const float* __restrict__ w3, const float* __restrict__ b3,
                                                  float* __restrict__ out) {
    __shared__ float buck[64];
    int tid = threadIdx.x;
    if (tid < 64) buck[tid] = 0.f;
    __syncthreads();
    int mol = blockIdx.y;
    float sign = mol ? 1.f : -1.f;
    const int* batch = mol ? batchp : batchr;
    const float* h_ = h64 + (size_t)mol * NN * 64;
    const float* u_ = up1 + (size_t)mol * NN * 112;
    const float* c_ = cnt + (size_t)mol * NN;
    float* xf_ = xf + (size_t)mol * NN * 16;
    int v = blockIdx.x * 256 + tid;
    float rc = 1.0f / fmaxf(c_[v], 1.0f);
    float xv[16];
#pragma unroll
    for (int c = 0; c < 16; c++) {
        xv[c] = fmaf(u_[v * 112 + c], rc, h_[v * 64 + c]);
        xf_[v * 16 + c] = xv[c];
    }
    float a[32];
#pragma unroll
    for (int j = 0; j < 32; j++) a[j] = b1[j];
#pragma unroll
    for (int i = 0; i < 16; i++) {
#pragma unroll
        for (int j = 0; j < 32; j++) a[j] = fmaf(xv[i], w1[i * 32 + j], a[j]);
    }
#pragma unroll
    for (int j = 0; j < 32; j++) a[j] = fmaxf(a[j], 0.f);
    float bb[16];
#pragma unroll
    for (int j = 0; j < 16; j++) bb[j] = b2[j];
#pragma unroll
    for (int i = 0; i < 32; i++) {
#pragma unroll
        for (int j = 0; j < 16; j++) bb[j] = fmaf(a[i], w2[i * 16 + j], bb[j]);
    }
#pragma unroll
    for (int j = 0; j < 16; j++) bb[j] = fmaxf(bb[j], 0.f);
    float val = b3[0];
#pragma unroll
    for (int i = 0; i < 16; i++) val = fmaf(bb[i], w3[i], val);
    atomicAdd(&buck[batch[v]], val);
    __syncthreads();
    if (tid < 64) atomicAdd(&out[tid], sign * buck[tid]);
}

// ---------------- s_edges MLP (64->16->16->1), bucket by batch[src] into out ----------------
__global__ __launch_bounds__(256) void k_sedge(const int* __restrict__ eir, const int* __restrict__ eip,
                                               const int* __restrict__ batchr, const int* __restrict__ batchp,
                                               const float* __restrict__ sh1d, const float* __restrict__ xf,
                                               const float* __restrict__ w1, const float* __restrict__ b1,
                                               const float* __restrict__ w2, const float* __restrict__ b2,
                                               const float* __restrict__ w3, const float* __restrict__ b3,
                                               float* __restrict__ out) {
    __shared__ float buck[64];
    int tid = threadIdx.x;
    if (tid < 64) buck[tid] = 0.f;
    __syncthreads();
    int mol = blockIdx.y;
    float sign = mol ? 1.f : -1.f;
    const int* ei = mol ? eip : eir;
    const int* batch = mol ? batchp : batchr;
    const float* sh_ = sh1d + (size_t)mol * NE * 4;
    const float* xf_ = xf + (size_t)mol * NN * 16;
    int e = blockIdx.x * 256 + tid;
    int s = ei[e], d = ei[NE + e];
    float dist = sh_[e * 4 + 3];
    float in[64];
#pragma unroll
    for (int i = 0; i < 32; i++) {
        float t = dist - (float)i * GSTEP;
        in[i] = __expf(GCOEFF * t * t);
    }
#pragma unroll
    for (int i = 0; i < 16; i++) in[32 + i] = xf_[s * 16 + i];
#pragma unroll
    for (int i = 0; i < 16; i++) in[48 + i] = xf_[d * 16 + i];
    float a[16];
#pragma unroll
    for (int j = 0; j < 16; j++) a[j] = b1[j];
#pragma unroll
    for (int i = 0; i < 64; i++) {
#pragma unroll
        for (int j = 0; j < 16; j++) a[j] = fmaf(in[i], w1[i * 16 + j], a[j]);
    }
#pragma unroll
    for (int j = 0; j < 16; j++) a[j] = fmaxf(a[j], 0.f);
    float bb[16];
#pragma unroll
    for (int j = 0; j < 16; j++) bb[j] = b2[j];
#pragma unroll
    for (int i = 0; i < 16; i++) {
#pragma unroll
        for (int j = 0; j < 16; j++) bb[j] = fmaf(a[i], w2[i * 16 + j], bb[j]);
    }
#pragma unroll
    for (int j = 0; j < 16; j++) bb[j] = fmaxf(bb[j], 0.f);
    float val = b3[0];
#pragma unroll
    for (int i = 0; i < 16; i++) val = fmaf(bb[i], w3[i], val);
    atomicAdd(&buck[batch[s]], val);
    __syncthreads();
    if (tid < 64) atomicAdd(&out[tid], sign * buck[tid]);
}

extern "C" void kernel_launch(void* const* d_in, const int* in_sizes, int n_in,
                              void* d_out, int out_size, void* d_ws, size_t ws_size,
                              hipStream_t stream) {
    const float* x_r = (const float*)d_in[0];
    const float* pos_r = (const float*)d_in[1];
    const int* ei_r = (const int*)d_in[2];
    const int* batch_r = (const int*)d_in[3];
    const float* x_p = (const float*)d_in[4];
    const float* pos_p = (const float*)d_in[5];
    const int* ei_p = (const int*)d_in[6];
    const int* batch_p = (const int*)d_in[7];
    const float* ne_w1 = (const float*)d_in[8];
    const float* ne_b1 = (const float*)d_in[9];
    const float* ne_w2 = (const float*)d_in[10];
    const float* ne_b2 = (const float*)d_in[11];
    const float* ee_w1 = (const float*)d_in[12];
    const float* ee_b1 = (const float*)d_in[13];
    const float* ee_w2 = (const float*)d_in[14];
    const float* ee_b2 = (const float*)d_in[15];
    const float* c0_w1 = (const float*)d_in[16];
    const float* c0_b1 = (const float*)d_in[17];
    const float* c0_w2 = (const float*)d_in[18];
    const float* c0_b2 = (const float*)d_in[19];
    const float* c1_w1 = (const float*)d_in[20];
    const float* c1_b1 = (const float*)d_in[21];
    const float* c1_w2 = (const float*)d_in[22];
    const float* c1_b2 = (const float*)d_in[23];
    const float* sn_w1 = (const float*)d_in[24];
    const float* sn_b1 = (const float*)d_in[25];
    const float* sn_w2 = (const float*)d_in[26];
    const float* sn_b2 = (const float*)d_in[27];
    const float* sn_w3 = (const float*)d_in[28];
    const float* sn_b3 = (const float*)d_in[29];
    const float* se_w1 = (const float*)d_in[30];
    const float* se_b1 = (const float*)d_in[31];
    const float* se_w2 = (const float*)d_in[32];
    const float* se_b2 = (const float*)d_in[33];
    const float* se_w3 = (const float*)d_in[34];
    const float* se_b3 = (const float*)d_in[35];
    float* out = (float*)d_out;

    char* p = (char*)d_ws;
    auto alloc = [&](size_t bytes) { char* r = p; p += (bytes + 255) & ~(size_t)255; return r; };
    f16* w2t1 = (f16*)alloc(1280 * 64 * 2);
    f16* w2t0 = (f16*)alloc(512 * 64 * 2);
    f16* w1c0 = (f16*)alloc(48 * 64 * 2);
    f16* w1c1 = (f16*)alloc(48 * 64 * 2);
    f16* eemb16 = (f16*)alloc((size_t)2 * NE * 16 * 2);
    f16* h16_16 = (f16*)alloc((size_t)2 * NN * 16 * 2);
    f16* h64_16 = (f16*)alloc((size_t)2 * NN * 16 * 2);
    float* h16f = (float*)alloc((size_t)2 * NN * 16 * 4);
    float* sh1d = (float*)alloc((size_t)2 * NE * 4 * 4);
    float* cnt  = (float*)alloc((size_t)2 * NN * 4);
    float* up0  = (float*)alloc((size_t)2 * NN * 64 * 4);
    float* h64f = (float*)alloc((size_t)2 * NN * 64 * 4);
    float* up1  = (float*)alloc((size_t)2 * NN * 112 * 4);
    float* xf   = (float*)alloc((size_t)2 * NN * 16 * 4);
    (void)ws_size; (void)n_in; (void)in_sizes; (void)out_size;

    hipMemsetAsync(up0, 0, (size_t)2 * NN * 64 * 4, stream);
    hipMemsetAsync(up1, 0, (size_t)2 * NN * 112 * 4, stream);
    hipMemsetAsync(cnt, 0, (size_t)2 * NN * 4, stream);
    hipMemsetAsync(out, 0, 64 * 4, stream);

    dim3 blk(256, 1, 1);
    dim3 gn(NN / 256, 2, 1);
    dim3 ge(NE / 256, 2, 1);
    dim3 gc(NE / 128, 2, 1);

    k_prep<<<dim3(320, 1, 1), blk, 0, stream>>>(c0_w1, c0_b1, c1_w1, c1_b1, c0_w2, c0_b2, c1_w2, c1_b2,
                                                w1c0, w1c1, w2t0, w2t1);
    k_node_mlp<<<gn, blk, 0, stream>>>(x_r, x_p, h16f, h16_16, ne_w1, ne_b1, ne_w2, ne_b2);
    k_edge_geom<<<ge, blk, 0, stream>>>(ei_r, ei_p, pos_r, pos_p, sh1d, eemb16, cnt,
                                        ee_w1, ee_b1, ee_w2, ee_b2);
    k_conv0<<<gc, blk, 0, stream>>>(ei_r, ei_p, eemb16, h16_16, h16f, sh1d, w1c0, w2t0, up0);
    k_up0<<<gn, blk, 0, stream>>>(h16f, up0, cnt, h64f, h64_16);
    k_conv1<<<gc, blk, 0, stream>>>(ei_r, ei_p, eemb16, h64_16, h64f, sh1d, w1c1, w2t1, up1);
    k_xf_snode<<<gn, blk, 0, stream>>>(h64f, up1, cnt, xf, batch_r, batch_p,
                                       sn_w1, sn_b1, sn_w2, sn_b2, sn_w3, sn_b3, out);
    k_sedge<<<ge, blk, 0, stream>>>(ei_r, ei_p, batch_r, batch_p, sh1d, xf,
                                    se_w1, se_b1, se_w2, se_b2, se_w3, se_b3, out);
}

// Round 5
// 194.577 us; speedup vs baseline: 14.9648x; 1.9932x over previous
//
#include <hip/hip_runtime.h>
#include <math.h>

#define NN 8192
#define NE 65536
#define SQRT3F 1.7320508075688772f
#define INV_SQRT3F 0.5773502691896258f
#define PW 0.17677669529663687f      // 1/sqrt(32) == 0.25/sqrt(2)
#define GSTEP (10.0f/31.0f)
#define GCOEFF (-0.5f/(GSTEP*GSTEP))

typedef _Float16 f16;
typedef f16 f16x2 __attribute__((ext_vector_type(2)));
typedef f16 f16x4 __attribute__((ext_vector_type(4)));
typedef f16 f16x8 __attribute__((ext_vector_type(8)));
typedef float f32x4 __attribute__((ext_vector_type(4)));

#define MFMA(acc, a, b) acc = __builtin_amdgcn_mfma_f32_16x16x32_f16(a, b, acc, 0, 0, 0)

// ---------------- prep: f16 weights, B-operand layout [n][k=64] (k48 = bias, rest 0) ----------------
__global__ __launch_bounds__(256) void k_prep(const float* __restrict__ c0w1, const float* __restrict__ c0b1,
                                              const float* __restrict__ c1w1, const float* __restrict__ c1b1,
                                              const float* __restrict__ c0w2, const float* __restrict__ c0b2,
                                              const float* __restrict__ c1w2, const float* __restrict__ c1b2,
                                              f16* __restrict__ w1c0, f16* __restrict__ w1c1,
                                              f16* __restrict__ w2t0, f16* __restrict__ w2t1) {
    int idx = blockIdx.x * 256 + threadIdx.x;    // grid covers 1280*64 = 81920
    if (idx >= 1280 * 64) return;
    int n = idx >> 6, h = idx & 63;
    w2t1[idx] = (f16)((h < 48) ? c1w2[h * 1280 + n] : (h == 48 ? c1b2[n] : 0.f));
    if (n < 512) w2t0[idx] = (f16)((h < 48) ? c0w2[h * 512 + n] : (h == 48 ? c0b2[n] : 0.f));
    if (n < 48) {
        w1c0[idx] = (f16)((h < 48) ? c0w1[h * 48 + n] : (h == 48 ? c0b1[n] : 0.f));
        w1c1[idx] = (f16)((h < 48) ? c1w1[h * 48 + n] : (h == 48 ? c1b1[n] : 0.f));
    }
}

// ---------------- node MLP: x(32) -> 16 -> 16 (f32 + f16 copy) ----------------
__global__ __launch_bounds__(256) void k_node_mlp(const float* __restrict__ xr, const float* __restrict__ xp,
                                                  float* __restrict__ h16, f16* __restrict__ h16_16,
                                                  const float* __restrict__ w1, const float* __restrict__ b1,
                                                  const float* __restrict__ w2, const float* __restrict__ b2) {
    int mol = blockIdx.y;
    const float* x = mol ? xp : xr;
    float* h = h16 + (size_t)mol * NN * 16;
    f16* h16o = h16_16 + (size_t)mol * NN * 16;
    int v = blockIdx.x * 256 + threadIdx.x;
    float xi[32];
#pragma unroll
    for (int i = 0; i < 32; i++) xi[i] = x[v * 32 + i];
    float a[16];
#pragma unroll
    for (int j = 0; j < 16; j++) a[j] = b1[j];
#pragma unroll
    for (int i = 0; i < 32; i++) {
#pragma unroll
        for (int j = 0; j < 16; j++) a[j] = fmaf(xi[i], w1[i * 16 + j], a[j]);
    }
#pragma unroll
    for (int j = 0; j < 16; j++) a[j] = fmaxf(a[j], 0.f);
    float o[16];
#pragma unroll
    for (int j = 0; j < 16; j++) o[j] = b2[j];
#pragma unroll
    for (int i = 0; i < 16; i++) {
#pragma unroll
        for (int j = 0; j < 16; j++) o[j] = fmaf(a[i], w2[i * 16 + j], o[j]);
    }
#pragma unroll
    for (int j = 0; j < 16; j++) { h[v * 16 + j] = o[j]; h16o[v * 16 + j] = (f16)o[j]; }
}

// ---------------- edge geometry + RBF + edge MLP (32->16->16, f16 out) + dst histogram ----------------
__global__ __launch_bounds__(256) void k_edge_geom(const int* __restrict__ eir, const int* __restrict__ eip,
                                                   const float* __restrict__ posr, const float* __restrict__ posp,
                                                   float* __restrict__ sh1d, f16* __restrict__ eemb16,
                                                   int* __restrict__ cnt,
                                                   const float* __restrict__ w1, const float* __restrict__ b1,
                                                   const float* __restrict__ w2, const float* __restrict__ b2) {
    int mol = blockIdx.y;
    const int* ei = mol ? eip : eir;
    const float* pos = mol ? posp : posr;
    float* sh_ = sh1d + (size_t)mol * NE * 4;
    f16* em_ = eemb16 + (size_t)mol * NE * 16;
    int* cn_ = cnt + mol * NN;
    int e = blockIdx.x * 256 + threadIdx.x;
    int s = ei[e], d = ei[NE + e];
    float ex = pos[d * 3 + 0] - pos[s * 3 + 0];
    float ey = pos[d * 3 + 1] - pos[s * 3 + 1];
    float ez = pos[d * 3 + 2] - pos[s * 3 + 2];
    float dist = sqrtf(ex * ex + ey * ey + ez * ez + 1e-12f);
    float inv = SQRT3F / dist;
    sh_[e * 4 + 0] = ex * inv;
    sh_[e * 4 + 1] = ey * inv;
    sh_[e * 4 + 2] = ez * inv;
    sh_[e * 4 + 3] = dist;
    float g[32];
#pragma unroll
    for (int i = 0; i < 32; i++) {
        float t = dist - (float)i * GSTEP;
        g[i] = __expf(GCOEFF * t * t);
    }
    float a[16];
#pragma unroll
    for (int j = 0; j < 16; j++) a[j] = b1[j];
#pragma unroll
    for (int i = 0; i < 32; i++) {
#pragma unroll
        for (int j = 0; j < 16; j++) a[j] = fmaf(g[i], w1[i * 16 + j], a[j]);
    }
#pragma unroll
    for (int j = 0; j < 16; j++) a[j] = fmaxf(a[j], 0.f);
    float o[16];
#pragma unroll
    for (int j = 0; j < 16; j++) o[j] = b2[j];
#pragma unroll
    for (int i = 0; i < 16; i++) {
#pragma unroll
        for (int j = 0; j < 16; j++) o[j] = fmaf(a[i], w2[i * 16 + j], o[j]);
    }
#pragma unroll
    for (int j = 0; j < 16; j++) em_[e * 16 + j] = (f16)o[j];
    atomicAdd(&cn_[d], 1);
}

// ---------------- CSR scan: per-mol exclusive prefix over cnt ----------------
__global__ __launch_bounds__(256) void k_scan(const int* __restrict__ cnt, int* __restrict__ rowptr) {
    __shared__ int part[256];
    int mol = blockIdx.x;
    const int* c = cnt + mol * NN;
    int* rp = rowptr + mol * (NN + 1);
    int t = threadIdx.x;
    int base = t * (NN / 256);
    int s = 0;
#pragma unroll
    for (int i = 0; i < NN / 256; i++) s += c[base + i];
    part[t] = s;
    __syncthreads();
    if (t == 0) {
        int run = 0;
        for (int i = 0; i < 256; i++) { int v = part[i]; part[i] = run; run += v; }
    }
    __syncthreads();
    int run = part[t];
    for (int i = 0; i < NN / 256; i++) { rp[base + i] = run; run += c[base + i]; }
    if (t == 255) rp[NN] = run;
}

// ---------------- CSR fill: eord[rowptr[d]+pos] = e ----------------
__global__ __launch_bounds__(256) void k_fill(const int* __restrict__ eir, const int* __restrict__ eip,
                                              const int* __restrict__ rowptr, int* __restrict__ fillc,
                                              int* __restrict__ eord) {
    int mol = blockIdx.y;
    const int* ei = mol ? eip : eir;
    int e = blockIdx.x * 256 + threadIdx.x;
    int d = ei[NE + e];
    int pos = atomicAdd(&fillc[mol * NN + d], 1);
    eord[mol * NE + rowptr[mol * (NN + 1) + d] + pos] = e;
}

// ======================= conv0: MFMA, 128 edges/block, 32/wave; stores tp0[e][4][16] =======================
__global__ __launch_bounds__(256) void k_conv0(const int* __restrict__ eir, const int* __restrict__ eip,
                                               const f16* __restrict__ eemb16, const f16* __restrict__ h16_16,
                                               const float* __restrict__ h16f, const float* __restrict__ sh1d,
                                               const f16* __restrict__ w1h, const f16* __restrict__ w2h,
                                               float* __restrict__ tp0) {
    __shared__ __align__(16) f16 ea[128 * 72];    // 144B/row; reused as hid
    __shared__ __align__(16) f16 sc0[128 * 24];   // 48B/row: 16 xu f16 + pad
    int mol = blockIdx.y;
    const int* ei = mol ? eip : eir;
    const f16* em_ = eemb16 + (size_t)mol * NE * 16;
    const f16* h16_ = h16_16 + (size_t)mol * NN * 16;
    const float* hf_ = h16f + (size_t)mol * NN * 16;
    const float* sh_ = sh1d + (size_t)mol * NE * 4;
    float* tp_ = tp0 + (size_t)mol * NE * 64;
    int tid = threadIdx.x;
    int e0 = blockIdx.x * 128;
    // ---- phase A: stage ea + scales (2 threads/edge, wave-private rows)
    {
        int er = tid >> 1, half = tid & 1;
        int e = e0 + er;
        int s = ei[e], d = ei[NE + e];
        char* row = (char*)ea + er * 144;
        if (half == 0) {
            const f16x8* p = (const f16x8*)(em_ + (size_t)e * 16);
            ((f16x8*)row)[0] = p[0]; ((f16x8*)row)[1] = p[1];
            const f16x8* q = (const f16x8*)(h16_ + (size_t)d * 16);
            ((f16x8*)row)[2] = q[0]; ((f16x8*)row)[3] = q[1];
        } else {
            const f16x8* q = (const f16x8*)(h16_ + (size_t)s * 16);
            ((f16x8*)row)[4] = q[0]; ((f16x8*)row)[5] = q[1];
            f16x8 z = {}; f16x8 o = {}; o[0] = (f16)1.0f;
            ((f16x8*)row)[6] = o; ((f16x8*)row)[7] = z; ((f16x8*)row)[8] = z;
        }
        int u0 = half * 8;
        float4 xa = *(const float4*)(hf_ + (size_t)s * 16 + u0);
        float4 xb = *(const float4*)(hf_ + (size_t)s * 16 + u0 + 4);
        f16x4 p0 = {(f16)xa.x, (f16)xa.y, (f16)xa.z, (f16)xa.w};
        f16x4 p1 = {(f16)xb.x, (f16)xb.y, (f16)xb.z, (f16)xb.w};
        *(f16x4*)((char*)sc0 + er * 48 + half * 16) = p0;
        *(f16x4*)((char*)sc0 + er * 48 + half * 16 + 8) = p1;
    }
    int wv = tid >> 6, l = tid & 63;
    int koff = (l >> 4) * 16;
    int voffB = (l & 15) * 128 + koff;
    int rbase = wv * 32;
    // ---- phase B: hid-gen
#pragma unroll
    for (int t = 0; t < 2; t++) {
        int arow = rbase + t * 16 + (l & 15);
        f16x8 a0 = *(const f16x8*)((const char*)ea + arow * 144 + koff);
        f16x8 a1 = *(const f16x8*)((const char*)ea + arow * 144 + koff + 64);
        f32x4 hacc[3];
#pragma unroll
        for (int nt = 0; nt < 3; nt++) {
            hacc[nt] = (f32x4){0.f, 0.f, 0.f, 0.f};
            const char* hb = (const char*)w1h + nt * 2048 + voffB;
            MFMA(hacc[nt], a0, *(const f16x8*)(hb));
            MFMA(hacc[nt], a1, *(const f16x8*)(hb + 64));
        }
#pragma unroll
        for (int nt = 0; nt < 3; nt++)
#pragma unroll
            for (int r = 0; r < 4; r++) {
                int rr = rbase + t * 16 + (l >> 4) * 4 + r;
                ea[rr * 72 + nt * 16 + (l & 15)] = (f16)fmaxf(hacc[nt][r], 0.f);
            }
    }
    f16x8 ha0[2], ha1[2];
#pragma unroll
    for (int t = 0; t < 2; t++) {
        int arow = rbase + t * 16 + (l & 15);
        ha0[t] = *(const f16x8*)((const char*)ea + arow * 144 + koff);
        ha1[t] = *(const f16x8*)((const char*)ea + arow * 144 + koff + 64);
    }
    // ---- phase C: K-loop over u, mats A(0), B(+32768), register double-buffer
    f32x4 accA[2] = {}, accB[2] = {};
    const char* wB = (const char*)w2h + voffB;
    f16x8 cA0 = *(const f16x8*)(wB), cA1 = *(const f16x8*)(wB + 64);
    f16x8 cB0 = *(const f16x8*)(wB + 32768), cB1 = *(const f16x8*)(wB + 32768 + 64);
#pragma unroll 4
    for (int u = 0; u < 16; ++u) {
        int un = (u < 15) ? u + 1 : 15;
        const char* Hb = wB + un * 2048;
        f16x8 nA0 = *(const f16x8*)(Hb), nA1 = *(const f16x8*)(Hb + 64);
        f16x8 nB0 = *(const f16x8*)(Hb + 32768), nB1 = *(const f16x8*)(Hb + 32768 + 64);
#pragma unroll
        for (int t = 0; t < 2; t++) {
            f16 s = *(const f16*)((const char*)sc0 + (rbase + t * 16 + (l & 15)) * 48 + u * 2);
            f16x8 x0 = ha0[t] * s, x1 = ha1[t] * s;
            MFMA(accA[t], x0, cA0); MFMA(accA[t], x1, cA1);
            MFMA(accB[t], x0, cB0); MFMA(accB[t], x1, cB1);
        }
        cA0 = nA0; cA1 = nA1; cB0 = nB0; cB1 = nB1;
    }
    // ---- epilogue: coalesced stores, comp-major [4][16]
    int w = l & 15;
#pragma unroll
    for (int t = 0; t < 2; t++)
#pragma unroll
        for (int r = 0; r < 4; r++) {
            int e = e0 + rbase + t * 16 + (l >> 4) * 4 + r;
            float4 shv = *(const float4*)(sh_ + (size_t)e * 4);
            float* tpp = tp_ + (size_t)e * 64;
            float tb = 0.25f * accB[t][r];
            tpp[w] = 0.25f * accA[t][r];
            tpp[16 + w] = tb * shv.x;
            tpp[32 + w] = tb * shv.y;
            tpp[48 + w] = tb * shv.z;
        }
}

// ---------------- gather conv0: h64 = pad(h16) + mean(tp0) (+ f16 copy of :16) ----------------
__global__ __launch_bounds__(256) void k_up0g(const float* __restrict__ h16, const float* __restrict__ tp0,
                                              const int* __restrict__ rowptr, const int* __restrict__ eord,
                                              float* __restrict__ h64, f16* __restrict__ h64_16) {
    int mol = blockIdx.y;
    const float* h_ = h16 + (size_t)mol * NN * 16;
    const float* tp = tp0 + (size_t)mol * NE * 64;
    const int* rp = rowptr + mol * (NN + 1);
    const int* eo = eord + mol * NE;
    float* o_ = h64 + (size_t)mol * NN * 64;
    f16* o16_ = h64_16 + (size_t)mol * NN * 16;
    int tid = threadIdx.x;
    int v = blockIdx.x * 64 + (tid >> 2), q = tid & 3;
    int r0 = rp[v], r1 = rp[v + 1];
    float acc[16];
#pragma unroll
    for (int j = 0; j < 16; j++) acc[j] = 0.f;
    for (int i = r0; i < r1; i++) {
        int e = eo[i];
        const float4* src = (const float4*)(tp + (size_t)e * 64 + q * 16);
#pragma unroll
        for (int j2 = 0; j2 < 4; j2++) {
            float4 vv = src[j2];
            acc[j2 * 4 + 0] += vv.x; acc[j2 * 4 + 1] += vv.y;
            acc[j2 * 4 + 2] += vv.z; acc[j2 * 4 + 3] += vv.w;
        }
    }
    float rc = 1.0f / fmaxf((float)(r1 - r0), 1.0f);
    if (q == 0) {
#pragma unroll
        for (int w = 0; w < 16; w++) {
            float val = fmaf(acc[w], rc, h_[(size_t)v * 16 + w]);
            o_[(size_t)v * 64 + w] = val;
            o16_[(size_t)v * 16 + w] = (f16)val;
        }
    } else {
#pragma unroll
        for (int w = 0; w < 16; w++) o_[(size_t)v * 64 + 16 + 3 * w + (q - 1)] = acc[w] * rc;
    }
}

// ======================= conv1: MFMA, mats A+D only (o0 is the only live output) =======================
__global__ __launch_bounds__(256) void k_conv1(const int* __restrict__ eir, const int* __restrict__ eip,
                                               const f16* __restrict__ eemb16, const f16* __restrict__ h64_16,
                                               const float* __restrict__ h64f, const float* __restrict__ sh1d,
                                               const f16* __restrict__ w1h, const f16* __restrict__ w2h,
                                               float* __restrict__ tp1) {
    __shared__ __align__(16) f16 ea[128 * 72];     // reused as hid
    __shared__ __align__(16) f16 sc[128 * 40];     // 80B/row: 16u x {xu,du} f16 + pad
    int mol = blockIdx.y;
    const int* ei = mol ? eip : eir;
    const f16* em_ = eemb16 + (size_t)mol * NE * 16;
    const f16* h16_ = h64_16 + (size_t)mol * NN * 16;
    const float* hf_ = h64f + (size_t)mol * NN * 64;
    const float* sh_ = sh1d + (size_t)mol * NE * 4;
    float* tp_ = tp1 + (size_t)mol * NE * 16;
    int tid = threadIdx.x;
    int e0 = blockIdx.x * 128;
    // ---- phase A
    {
        int er = tid >> 1, half = tid & 1;
        int e = e0 + er;
        int s = ei[e], d = ei[NE + e];
        char* row = (char*)ea + er * 144;
        if (half == 0) {
            const f16x8* p = (const f16x8*)(em_ + (size_t)e * 16);
            ((f16x8*)row)[0] = p[0]; ((f16x8*)row)[1] = p[1];
            const f16x8* q = (const f16x8*)(h16_ + (size_t)d * 16);
            ((f16x8*)row)[2] = q[0]; ((f16x8*)row)[3] = q[1];
        } else {
            const f16x8* q = (const f16x8*)(h16_ + (size_t)s * 16);
            ((f16x8*)row)[4] = q[0]; ((f16x8*)row)[5] = q[1];
            f16x8 z = {}; f16x8 o = {}; o[0] = (f16)1.0f;
            ((f16x8*)row)[6] = o; ((f16x8*)row)[7] = z; ((f16x8*)row)[8] = z;
        }
        float4 shv = *(const float4*)(sh_ + (size_t)e * 4);
        const float* hfs = hf_ + (size_t)s * 64;
        int u0 = half * 8;
        float4 xa = *(const float4*)(hfs + u0);
        float4 xb = *(const float4*)(hfs + u0 + 4);
        float xuv[8] = {xa.x, xa.y, xa.z, xa.w, xb.x, xb.y, xb.z, xb.w};
        float x1[24];
#pragma unroll
        for (int q2 = 0; q2 < 6; q2++) {
            float4 v = *(const float4*)(hfs + 16 + u0 * 3 + q2 * 4);
            x1[q2 * 4 + 0] = v.x; x1[q2 * 4 + 1] = v.y; x1[q2 * 4 + 2] = v.z; x1[q2 * 4 + 3] = v.w;
        }
#pragma unroll
        for (int k2 = 0; k2 < 4; k2++) {
            int ka = 2 * k2, kb = 2 * k2 + 1;
            float dua = (x1[ka * 3] * shv.x + x1[ka * 3 + 1] * shv.y + x1[ka * 3 + 2] * shv.z) * INV_SQRT3F;
            float dub = (x1[kb * 3] * shv.x + x1[kb * 3 + 1] * shv.y + x1[kb * 3 + 2] * shv.z) * INV_SQRT3F;
            f16x4 pv = {(f16)xuv[ka], (f16)dua, (f16)xuv[kb], (f16)dub};
            *(f16x4*)((char*)sc + er * 80 + half * 32 + k2 * 8) = pv;
        }
    }
    int wv = tid >> 6, l = tid & 63;
    int koff = (l >> 4) * 16;
    int voffB = (l & 15) * 128 + koff;
    int rbase = wv * 32;
    // ---- phase B: hid-gen
#pragma unroll
    for (int t = 0; t < 2; t++) {
        int arow = rbase + t * 16 + (l & 15);
        f16x8 a0 = *(const f16x8*)((const char*)ea + arow * 144 + koff);
        f16x8 a1 = *(const f16x8*)((const char*)ea + arow * 144 + koff + 64);
        f32x4 hacc[3];
#pragma unroll
        for (int nt = 0; nt < 3; nt++) {
            hacc[nt] = (f32x4){0.f, 0.f, 0.f, 0.f};
            const char* hb = (const char*)w1h + nt * 2048 + voffB;
            MFMA(hacc[nt], a0, *(const f16x8*)(hb));
            MFMA(hacc[nt], a1, *(const f16x8*)(hb + 64));
        }
#pragma unroll
        for (int nt = 0; nt < 3; nt++)
#pragma unroll
            for (int r = 0; r < 4; r++) {
                int rr = rbase + t * 16 + (l >> 4) * 4 + r;
                ea[rr * 72 + nt * 16 + (l & 15)] = (f16)fmaxf(hacc[nt][r], 0.f);
            }
    }
    f16x8 ha0[2], ha1[2];
#pragma unroll
    for (int t = 0; t < 2; t++) {
        int arow = rbase + t * 16 + (l & 15);
        ha0[t] = *(const f16x8*)((const char*)ea + arow * 144 + koff);
        ha1[t] = *(const f16x8*)((const char*)ea + arow * 144 + koff + 64);
    }
    // ---- phase C: K-loop over u. Mats A (0 B) and D (98304 B); acc = Σ xu·(hid·A) + du·(hid·D)
    f32x4 accA[2] = {};
    const char* wB = (const char*)w2h + voffB;
    f16x8 cA0 = *(const f16x8*)(wB), cA1 = *(const f16x8*)(wB + 64);
    f16x8 cD0 = *(const f16x8*)(wB + 98304), cD1 = *(const f16x8*)(wB + 98304 + 64);
#pragma unroll 4
    for (int u = 0; u < 16; ++u) {
        int un = (u < 15) ? u + 1 : 15;
        const char* Hb = wB + un * 2048;
        f16x8 nA0 = *(const f16x8*)(Hb), nA1 = *(const f16x8*)(Hb + 64);
        f16x8 nD0 = *(const f16x8*)(Hb + 98304), nD1 = *(const f16x8*)(Hb + 98304 + 64);
#pragma unroll
        for (int t = 0; t < 2; t++) {
            f16x2 sp = *(const f16x2*)((const char*)sc + (rbase + t * 16 + (l & 15)) * 80 + u * 4);
            f16x8 x0 = ha0[t] * sp[0], x1 = ha1[t] * sp[0];
            MFMA(accA[t], x0, cA0); MFMA(accA[t], x1, cA1);
            x0 = ha0[t] * sp[1]; x1 = ha1[t] * sp[1];
            MFMA(accA[t], x0, cD0); MFMA(accA[t], x1, cD1);
        }
        cA0 = nA0; cA1 = nA1; cD0 = nD0; cD1 = nD1;
    }
    // ---- epilogue: tp1[e][16]
    int w = l & 15;
#pragma unroll
    for (int t = 0; t < 2; t++)
#pragma unroll
        for (int r = 0; r < 4; r++) {
            int e = e0 + rbase + t * 16 + (l >> 4) * 4 + r;
            tp_[(size_t)e * 16 + w] = PW * accA[t][r];
        }
}

// ---------------- gather conv1 -> xf; s_nodes MLP; bucket into out ----------------
__global__ __launch_bounds__(256) void k_xfg(const float* __restrict__ h64, const float* __restrict__ tp1,
                                             const int* __restrict__ rowptr, const int* __restrict__ eord,
                                             float* __restrict__ xf,
                                             const int* __restrict__ batchr, const int* __restrict__ batchp,
                                             const float* __restrict__ w1, const float* __restrict__ b1,
                                             const float* __restrict__ w2, const float* __restrict__ b2,
                                             const float* __restrict__ w3, const float* __restrict__ b3,
                                             float* __restrict__ out) {
    __shared__ float xfs[64][17];
    __shared__ float buck[64];
    int tid = threadIdx.x;
    if (tid < 64) buck[tid] = 0.f;
    int mol = blockIdx.y;
    float sign = mol ? 1.f : -1.f;
    const int* batch = mol ? batchp : batchr;
    const float* h_ = h64 + (size_t)mol * NN * 64;
    const float* tp = tp1 + (size_t)mol * NE * 16;
    const int* rp = rowptr + mol * (NN + 1);
    const int* eo = eord + mol * NE;
    float* xf_ = xf + (size_t)mol * NN * 16;
    int v = blockIdx.x * 64 + (tid >> 2), q = tid & 3;
    int r0 = rp[v], r1 = rp[v + 1];
    float4 a = {0.f, 0.f, 0.f, 0.f};
    for (int i = r0; i < r1; i++) {
        int e = eo[i];
        float4 t4 = *(const float4*)(tp + (size_t)e * 16 + q * 4);
        a.x += t4.x; a.y += t4.y; a.z += t4.z; a.w += t4.w;
    }
    float rc = 1.0f / fmaxf((float)(r1 - r0), 1.0f);
    float4 hv = *(const float4*)(h_ + (size_t)v * 64 + q * 4);
    float4 xv4;
    xv4.x = fmaf(a.x, rc, hv.x); xv4.y = fmaf(a.y, rc, hv.y);
    xv4.z = fmaf(a.z, rc, hv.z); xv4.w = fmaf(a.w, rc, hv.w);
    xfs[tid >> 2][q * 4 + 0] = xv4.x; xfs[tid >> 2][q * 4 + 1] = xv4.y;
    xfs[tid >> 2][q * 4 + 2] = xv4.z; xfs[tid >> 2][q * 4 + 3] = xv4.w;
    *(float4*)(xf_ + (size_t)v * 16 + q * 4) = xv4;
    __syncthreads();
    if (tid < 64) {
        int v2 = blockIdx.x * 64 + tid;
        float xv[16];
#pragma unroll
        for (int c = 0; c < 16; c++) xv[c] = xfs[tid][c];
        float aa[32];
#pragma unroll
        for (int j = 0; j < 32; j++) aa[j] = b1[j];
#pragma unroll
        for (int i = 0; i < 16; i++) {
#pragma unroll
            for (int j = 0; j < 32; j++) aa[j] = fmaf(xv[i], w1[i * 32 + j], aa[j]);
        }
#pragma unroll
        for (int j = 0; j < 32; j++) aa[j] = fmaxf(aa[j], 0.f);
        float bb[16];
#pragma unroll
        for (int j = 0; j < 16; j++) bb[j] = b2[j];
#pragma unroll
        for (int i = 0; i < 32; i++) {
#pragma unroll
            for (int j = 0; j < 16; j++) bb[j] = fmaf(aa[i], w2[i * 16 + j], bb[j]);
        }
#pragma unroll
        for (int j = 0; j < 16; j++) bb[j] = fmaxf(bb[j], 0.f);
        float val = b3[0];
#pragma unroll
        for (int i = 0; i < 16; i++) val = fmaf(bb[i], w3[i], val);
        atomicAdd(&buck[batch[v2]], val);
    }
    __syncthreads();
    if (tid < 64) atomicAdd(&out[tid], sign * buck[tid]);
}

// ---------------- s_edges MLP (64->16->16->1), bucket by batch[src] into out ----------------
__global__ __launch_bounds__(256) void k_sedge(const int* __restrict__ eir, const int* __restrict__ eip,
                                               const int* __restrict__ batchr, const int* __restrict__ batchp,
                                               const float* __restrict__ sh1d, const float* __restrict__ xf,
                                               const float* __restrict__ w1, const float* __restrict__ b1,
                                               const float* __restrict__ w2, const float* __restrict__ b2,
                                               const float* __restrict__ w3, const float* __restrict__ b3,
                                               float* __restrict__ out) {
    __shared__ float buck[64];
    int tid = threadIdx.x;
    if (tid < 64) buck[tid] = 0.f;
    __syncthreads();
    int mol = blockIdx.y;
    float sign = mol ? 1.f : -1.f;
    const int* ei = mol ? eip : eir;
    const int* batch = mol ? batchp : batchr;
    const float* sh_ = sh1d + (size_t)mol * NE * 4;
    const float* xf_ = xf + (size_t)mol * NN * 16;
    int e = blockIdx.x * 256 + tid;
    int s = ei[e], d = ei[NE + e];
    float dist = sh_[e * 4 + 3];
    float in[64];
#pragma unroll
    for (int i = 0; i < 32; i++) {
        float t = dist - (float)i * GSTEP;
        in[i] = __expf(GCOEFF * t * t);
    }
#pragma unroll
    for (int i = 0; i < 16; i++) in[32 + i] = xf_[s * 16 + i];
#pragma unroll
    for (int i = 0; i < 16; i++) in[48 + i] = xf_[d * 16 + i];
    float a[16];
#pragma unroll
    for (int j = 0; j < 16; j++) a[j] = b1[j];
#pragma unroll
    for (int i = 0; i < 64; i++) {
#pragma unroll
        for (int j = 0; j < 16; j++) a[j] = fmaf(in[i], w1[i * 16 + j], a[j]);
    }
#pragma unroll
    for (int j = 0; j < 16; j++) a[j] = fmaxf(a[j], 0.f);
    float bb[16];
#pragma unroll
    for (int j = 0; j < 16; j++) bb[j] = b2[j];
#pragma unroll
    for (int i = 0; i < 16; i++) {
#pragma unroll
        for (int j = 0; j < 16; j++) bb[j] = fmaf(a[i], w2[i * 16 + j], bb[j]);
    }
#pragma unroll
    for (int j = 0; j < 16; j++) bb[j] = fmaxf(bb[j], 0.f);
    float val = b3[0];
#pragma unroll
    for (int i = 0; i < 16; i++) val = fmaf(bb[i], w3[i], val);
    atomicAdd(&buck[batch[s]], val);
    __syncthreads();
    if (tid < 64) atomicAdd(&out[tid], sign * buck[tid]);
}

extern "C" void kernel_launch(void* const* d_in, const int* in_sizes, int n_in,
                              void* d_out, int out_size, void* d_ws, size_t ws_size,
                              hipStream_t stream) {
    const float* x_r = (const float*)d_in[0];
    const float* pos_r = (const float*)d_in[1];
    const int* ei_r = (const int*)d_in[2];
    const int* batch_r = (const int*)d_in[3];
    const float* x_p = (const float*)d_in[4];
    const float* pos_p = (const float*)d_in[5];
    const int* ei_p = (const int*)d_in[6];
    const int* batch_p = (const int*)d_in[7];
    const float* ne_w1 = (const float*)d_in[8];
    const float* ne_b1 = (const float*)d_in[9];
    const float* ne_w2 = (const float*)d_in[10];
    const float* ne_b2 = (const float*)d_in[11];
    const float* ee_w1 = (const float*)d_in[12];
    const float* ee_b1 = (const float*)d_in[13];
    const float* ee_w2 = (const float*)d_in[14];
    const float* ee_b2 = (const float*)d_in[15];
    const float* c0_w1 = (const float*)d_in[16];
    const float* c0_b1 = (const float*)d_in[17];
    const float* c0_w2 = (const float*)d_in[18];
    const float* c0_b2 = (const float*)d_in[19];
    const float* c1_w1 = (const float*)d_in[20];
    const float* c1_b1 = (const float*)d_in[21];
    const float* c1_w2 = (const float*)d_in[22];
    const float* c1_b2 = (const float*)d_in[23];
    const float* sn_w1 = (const float*)d_in[24];
    const float* sn_b1 = (const float*)d_in[25];
    const float* sn_w2 = (const float*)d_in[26];
    const float* sn_b2 = (const float*)d_in[27];
    const float* sn_w3 = (const float*)d_in[28];
    const float* sn_b3 = (const float*)d_in[29];
    const float* se_w1 = (const float*)d_in[30];
    const float* se_b1 = (const float*)d_in[31];
    const float* se_w2 = (const float*)d_in[32];
    const float* se_b2 = (const float*)d_in[33];
    const float* se_w3 = (const float*)d_in[34];
    const float* se_b3 = (const float*)d_in[35];
    float* out = (float*)d_out;

    char* p = (char*)d_ws;
    auto alloc = [&](size_t bytes) { char* r = p; p += (bytes + 255) & ~(size_t)255; return r; };
    f16* w2t1 = (f16*)alloc(1280 * 64 * 2);
    f16* w2t0 = (f16*)alloc(512 * 64 * 2);
    f16* w1c0 = (f16*)alloc(48 * 64 * 2);
    f16* w1c1 = (f16*)alloc(48 * 64 * 2);
    f16* eemb16 = (f16*)alloc((size_t)2 * NE * 16 * 2);
    f16* h16_16 = (f16*)alloc((size_t)2 * NN * 16 * 2);
    f16* h64_16 = (f16*)alloc((size_t)2 * NN * 16 * 2);
    float* h16f = (float*)alloc((size_t)2 * NN * 16 * 4);
    float* sh1d = (float*)alloc((size_t)2 * NE * 4 * 4);
    int* cntI = (int*)alloc((size_t)2 * NN * 4);
    int* rowptr = (int*)alloc((size_t)2 * (NN + 1) * 4);
    int* fillc = (int*)alloc((size_t)2 * NN * 4);
    int* eord = (int*)alloc((size_t)2 * NE * 4);
    float* tp0 = (float*)alloc((size_t)2 * NE * 64 * 4);
    float* tp1 = tp0;                                    // reused after k_up0g consumes tp0
    float* h64f = (float*)alloc((size_t)2 * NN * 64 * 4);
    float* xf = (float*)alloc((size_t)2 * NN * 16 * 4);
    (void)ws_size; (void)n_in; (void)in_sizes; (void)out_size;

    hipMemsetAsync(cntI, 0, (size_t)2 * NN * 4, stream);
    hipMemsetAsync(fillc, 0, (size_t)2 * NN * 4, stream);
    hipMemsetAsync(out, 0, 64 * 4, stream);

    dim3 blk(256, 1, 1);
    dim3 gn(NN / 256, 2, 1);
    dim3 ge(NE / 256, 2, 1);
    dim3 gc(NE / 128, 2, 1);
    dim3 gu(NN / 64, 2, 1);

    k_prep<<<dim3(320, 1, 1), blk, 0, stream>>>(c0_w1, c0_b1, c1_w1, c1_b1, c0_w2, c0_b2, c1_w2, c1_b2,
                                                w1c0, w1c1, w2t0, w2t1);
    k_node_mlp<<<gn, blk, 0, stream>>>(x_r, x_p, h16f, h16_16, ne_w1, ne_b1, ne_w2, ne_b2);
    k_edge_geom<<<ge, blk, 0, stream>>>(ei_r, ei_p, pos_r, pos_p, sh1d, eemb16, cntI,
                                        ee_w1, ee_b1, ee_w2, ee_b2);
    k_scan<<<dim3(2, 1, 1), blk, 0, stream>>>(cntI, rowptr);
    k_fill<<<ge, blk, 0, stream>>>(ei_r, ei_p, rowptr, fillc, eord);
    k_conv0<<<gc, blk, 0, stream>>>(ei_r, ei_p, eemb16, h16_16, h16f, sh1d, w1c0, w2t0, tp0);
    k_up0g<<<gu, blk, 0, stream>>>(h16f, tp0, rowptr, eord, h64f, h64_16);
    k_conv1<<<gc, blk, 0, stream>>>(ei_r, ei_p, eemb16, h64_16, h64f, sh1d, w1c1, w2t1, tp1);
    k_xfg<<<gu, blk, 0, stream>>>(h64f, tp1, rowptr, eord, xf, batch_r, batch_p,
                                  sn_w1, sn_b1, sn_w2, sn_b2, sn_w3, sn_b3, out);
    k_sedge<<<ge, blk, 0, stream>>>(ei_r, ei_p, batch_r, batch_p, sh1d, xf,
                                    se_w1, se_b1, se_w2, se_b2, se_w3, se_b3, out);
}